// Round 1
// baseline (459.140 us; speedup 1.0000x reference)
//
#include <hip/hip_runtime.h>

// GateLoopOperator, MI355X. Round 1: all-f32 correctness-first implementation.
// Shapes: B=4,P=2,T=32 (BP=8, M=256 bpt), NLAT=8, NSP=64 (CX=512), NE=100.
//
// Pipeline:
//  k_kqv : k/q/v[m,C,X] = sum_{c,x} {K,Q,V}[X,C,x,c] * x[m,c,x]      (256x512x512 x3)
//  k_tmp : tmp[m,(k2,y,n)] = sum_{(c,x)} k[m,cx] * Ano[c,k2,x,y,n]   (256x512x51200 GEMM)
//  k_S   : S[m,n] = sum_{ky} tmp[m,ky*100+n] * v[m,ky]
//  k_scan: u[bp,n] = S[bp,30] + sum_i Ann^(2^i) @ S[bp,29-i]  (single block, serial squaring,
//          early exit when max|A| < 1e-28 — terms then contribute < 1e-23 vs threshold 15.76)
//  k_h   : h[bp,a,b,g,d] = Aoo[a,b,g,d]*k_last[bp,a,g]*v_last[bp,b,d] + sum_n Aon[a,b,g,d,n]*u[bp,n]
//  k_y   : y[bpt,b,d] = sum_{a,g} q[bpt,a*64+g] * h[bp,a,b,g,d]
//
// ws usage (floats): kw 131072 | qw 131072 | vw 131072 | tmp 13107200 | S 25600 | u 800 | h 2097152
// total = 15,623,968 floats = 59.6 MiB.

#define ANO_C_STR 3276800
#define ANO_K_STR 409600
#define ANO_X_STR 6400

__device__ __forceinline__ float4 ld4(const float* p) { return *(const float4*)p; }

// ---------------------------------------------------------------- k_kqv
__global__ __launch_bounds__(256) void k_kqv(const float* __restrict__ X,
                                             const float* __restrict__ Km,
                                             const float* __restrict__ Qm,
                                             const float* __restrict__ Vm,
                                             float* __restrict__ kw,
                                             float* __restrict__ qw,
                                             float* __restrict__ vw) {
  __shared__ float xs[512];  // permuted: xs[x*8+c] = X[m, c, x]
  const int m = blockIdx.x;
  const int tid = threadIdx.x;
  for (int f = tid; f < 512; f += 256) {
    int c = f >> 6, x = f & 63;
    xs[(x << 3) | c] = X[m * 512 + f];
  }
  __syncthreads();
  const float4* xp = (const float4*)xs;
  for (int o = tid; o < 512; o += 256) {
    const int C = o >> 6, Xo = o & 63;
    const size_t base = (size_t)Xo * 4096 + (size_t)C * 512;
    const float4* kr = (const float4*)(Km + base);
    const float4* qr = (const float4*)(Qm + base);
    const float4* vr = (const float4*)(Vm + base);
    float ak = 0.f, aq = 0.f, av = 0.f;
#pragma unroll 4
    for (int j4 = 0; j4 < 128; ++j4) {
      float4 xv = xp[j4];
      float4 k4 = kr[j4];
      float4 q4 = qr[j4];
      float4 v4 = vr[j4];
      ak += k4.x * xv.x + k4.y * xv.y + k4.z * xv.z + k4.w * xv.w;
      aq += q4.x * xv.x + q4.y * xv.y + q4.z * xv.z + q4.w * xv.w;
      av += v4.x * xv.x + v4.y * xv.y + v4.z * xv.z + v4.w * xv.w;
    }
    kw[m * 512 + o] = ak;
    qw[m * 512 + o] = aq;
    vw[m * 512 + o] = av;
  }
}

// ---------------------------------------------------------------- k_tmp
// GEMM: tmp[M=256, J=51200] = k[256, 512] @ AnoMat[512, 51200]
// AnoMat[(c,x), j=(k2,y,n)] = Ano[c,k2,x,y,n].
// Tiles: M-tile 64, J-tile 256, K-chunk 16. 8x8 register microtile per thread
// (rows {r3*4..+4, 32+r3*4..+4}, cols {c3*4..+4, 128+c3*4..+4} -> conflict-free b128).
// bid = mt*200 + jt so the 4 m-tiles of one jt are 200 apart (200%8==0 -> same XCD -> L2 reuse of Ano).
__global__ __launch_bounds__(256) void k_tmp(const float* __restrict__ kw,
                                             const float* __restrict__ Ano,
                                             float* __restrict__ tmp) {
  __shared__ float ksT[16 * 64];   // [kk][mm]
  __shared__ float As[16 * 256];   // [kk][jj]
  __shared__ int coff[256];
  const int bid = blockIdx.x;      // 0..799
  const int mt = bid / 200;
  const int jt = bid % 200;
  const int m0 = mt * 64;
  const int j0 = jt * 256;
  const int tid = threadIdx.x;

  {
    int j = j0 + tid;
    int k2 = j / 6400;
    int rem = j - k2 * 6400;
    int y = rem / 100;
    int n = rem - y * 100;
    coff[tid] = k2 * ANO_K_STR + y * 100 + n;
  }

  const int r3 = tid >> 5;  // 0..7
  const int c3 = tid & 31;  // 0..31
  float acc[8][8];
#pragma unroll
  for (int r = 0; r < 8; ++r)
#pragma unroll
    for (int cc = 0; cc < 8; ++cc) acc[r][cc] = 0.f;

  __syncthreads();

  for (int kc = 0; kc < 512; kc += 16) {
    // stage ksT (transposed k panel)
    {
      int mm = tid & 63, kq = tid >> 6;  // kq 0..3
      float4 kv = ld4(kw + (size_t)(m0 + mm) * 512 + kc + kq * 4);
      ksT[(kq * 4 + 0) * 64 + mm] = kv.x;
      ksT[(kq * 4 + 1) * 64 + mm] = kv.y;
      ksT[(kq * 4 + 2) * 64 + mm] = kv.z;
      ksT[(kq * 4 + 3) * 64 + mm] = kv.w;
    }
    // stage As
#pragma unroll
    for (int q = 0; q < 16; ++q) {
      int idx = q * 256 + tid;         // kk = q, jj = tid
      int a = kc + q;
      As[idx] = Ano[(size_t)(a >> 6) * ANO_C_STR + (size_t)(a & 63) * ANO_X_STR + coff[tid]];
    }
    __syncthreads();
#pragma unroll
    for (int kk = 0; kk < 16; ++kk) {
      float ka[8], aa[8];
      *(float4*)&ka[0] = ld4(&ksT[kk * 64 + r3 * 4]);
      *(float4*)&ka[4] = ld4(&ksT[kk * 64 + 32 + r3 * 4]);
      *(float4*)&aa[0] = ld4(&As[kk * 256 + c3 * 4]);
      *(float4*)&aa[4] = ld4(&As[kk * 256 + 128 + c3 * 4]);
#pragma unroll
      for (int r = 0; r < 8; ++r)
#pragma unroll
        for (int cc = 0; cc < 8; ++cc) acc[r][cc] += ka[r] * aa[cc];
    }
    __syncthreads();
  }

#pragma unroll
  for (int r = 0; r < 8; ++r) {
    int row = m0 + ((r < 4) ? (r3 * 4 + r) : (32 + r3 * 4 + (r - 4)));
    float4 v0 = make_float4(acc[r][0], acc[r][1], acc[r][2], acc[r][3]);
    float4 v1 = make_float4(acc[r][4], acc[r][5], acc[r][6], acc[r][7]);
    *(float4*)&tmp[(size_t)row * 51200 + j0 + c3 * 4] = v0;
    *(float4*)&tmp[(size_t)row * 51200 + j0 + 128 + c3 * 4] = v1;
  }
}

// ---------------------------------------------------------------- k_S
__global__ __launch_bounds__(128) void k_S(const float* __restrict__ tmp,
                                           const float* __restrict__ vw,
                                           float* __restrict__ S) {
  __shared__ float vs[512];
  const int m = blockIdx.x;
  const int tid = threadIdx.x;
  for (int f = tid; f < 512; f += 128) vs[f] = vw[m * 512 + f];
  __syncthreads();
  if (tid < 100) {
    const float* tr = tmp + (size_t)m * 51200 + tid;
    float acc = 0.f;
#pragma unroll 8
    for (int ky = 0; ky < 512; ++ky) acc += tr[ky * 100] * vs[ky];
    S[m * 100 + tid] = acc;
  }
}

// ---------------------------------------------------------------- k_scan
// Single block. A (100x100) lives in LDS; squaring is computed fully into
// registers (4x4 tile per thread, 625 active), then written back in place.
__global__ __launch_bounds__(1024) void k_scan(const float* __restrict__ Ann,
                                               const float* __restrict__ Sg,
                                               float* __restrict__ ug) {
  __shared__ float Abuf[10000];
  __shared__ float s_s[800];
  __shared__ float u_s[800];
  __shared__ float red[16];
  __shared__ int stopflag;
  const int tid = threadIdx.x;

  for (int f = tid; f < 10000; f += 1024) Abuf[f] = Ann[f];
  for (int f = tid; f < 800; f += 1024) {
    int bp = f / 100, n = f - bp * 100;
    u_s[f] = Sg[(bp * 32 + 30) * 100 + n];
  }
  const int ri = tid / 25;       // 0..24 when active
  const int cj = tid - ri * 25;  // 0..24
  const bool sqact = (tid < 625);
  __syncthreads();

  for (int i = 0; i < 30; ++i) {
    const int t = 29 - i;
    for (int f = tid; f < 800; f += 1024) {
      int bp = f / 100, n = f - bp * 100;
      s_s[f] = Sg[(bp * 32 + t) * 100 + n];
    }
    __syncthreads();
    if (tid < 800) {
      int bp = tid / 100, n = tid - bp * 100;
      const float* Ar = &Abuf[n * 100];
      const float* sr = &s_s[bp * 100];
      float a0 = 0.f;
#pragma unroll
      for (int mm = 0; mm < 100; mm += 4) {
        float4 a4 = ld4(Ar + mm);
        float4 s4 = ld4(sr + mm);
        a0 += a4.x * s4.x + a4.y * s4.y + a4.z * s4.z + a4.w * s4.w;
      }
      u_s[tid] += a0;
    }
    if (i == 29) break;

    float acc2[4][4];
    float lmax = 0.f;
    if (sqact) {
#pragma unroll
      for (int a = 0; a < 4; ++a)
#pragma unroll
        for (int b = 0; b < 4; ++b) acc2[a][b] = 0.f;
      for (int mm = 0; mm < 100; mm += 4) {
        float av[4][4], bv[4][4];
#pragma unroll
        for (int ii = 0; ii < 4; ++ii)
          *(float4*)&av[ii][0] = ld4(&Abuf[(ri * 4 + ii) * 100 + mm]);
#pragma unroll
        for (int mi = 0; mi < 4; ++mi)
          *(float4*)&bv[mi][0] = ld4(&Abuf[(mm + mi) * 100 + cj * 4]);
#pragma unroll
        for (int ii = 0; ii < 4; ++ii)
#pragma unroll
          for (int mi = 0; mi < 4; ++mi)
#pragma unroll
            for (int qq = 0; qq < 4; ++qq) acc2[ii][qq] += av[ii][mi] * bv[mi][qq];
      }
    }
    __syncthreads();  // all reads of Abuf complete before in-place overwrite
    if (sqact) {
#pragma unroll
      for (int ii = 0; ii < 4; ++ii) {
        float4 w = make_float4(acc2[ii][0], acc2[ii][1], acc2[ii][2], acc2[ii][3]);
        *(float4*)&Abuf[(ri * 4 + ii) * 100 + cj * 4] = w;
        lmax = fmaxf(lmax, fmaxf(fmaxf(fabsf(w.x), fabsf(w.y)), fmaxf(fabsf(w.z), fabsf(w.w))));
      }
    }
#pragma unroll
    for (int off = 32; off > 0; off >>= 1) lmax = fmaxf(lmax, __shfl_down(lmax, off, 64));
    if ((tid & 63) == 0) red[tid >> 6] = lmax;
    __syncthreads();
    if (tid == 0) {
      float mx = 0.f;
      for (int w = 0; w < 16; ++w) mx = fmaxf(mx, red[w]);
      stopflag = (mx < 1e-28f) ? 1 : 0;
    }
    __syncthreads();
    if (stopflag) break;  // remaining terms contribute < 1e-23 (threshold 15.76)
  }
  __syncthreads();
  for (int f = tid; f < 800; f += 1024) ug[f] = u_s[f];
}

// ---------------------------------------------------------------- k_h
// block = (a,b,g) = ((c*8+k2)*64+x); thread (ng 0..3, d 0..63).
// Aon row chunk held in registers (coalesced: addr = (tid*25 + q)*4B across lanes).
__global__ __launch_bounds__(256) void k_h(const float* __restrict__ Aon,
                                           const float* __restrict__ Aoo,
                                           const float* __restrict__ kw,
                                           const float* __restrict__ vw,
                                           const float* __restrict__ ug,
                                           float* __restrict__ h) {
  __shared__ float uT[100 * 8];    // [n][bp]
  __shared__ float aoo_s[64];
  __shared__ float kl_s[8];
  __shared__ float vl_s[8 * 64];   // [bp][d]
  __shared__ float part[4 * 64 * 8];
  const int bid = blockIdx.x;      // (a*8+b)*64+g
  const int g = bid & 63, b = (bid >> 6) & 7, a = bid >> 9;
  const int tid = threadIdx.x;

  for (int f = tid; f < 800; f += 256) {
    int n = f >> 3, bp = f & 7;
    uT[f] = ug[bp * 100 + n];
  }
  if (tid < 64) aoo_s[tid] = Aoo[(size_t)bid * 64 + tid];
  if (tid < 8) kl_s[tid] = kw[(size_t)(tid * 32 + 31) * 512 + a * 64 + g];
  for (int f = tid; f < 512; f += 256) {
    int bp = f >> 6, d = f & 63;
    vl_s[f] = vw[(size_t)(bp * 32 + 31) * 512 + b * 64 + d];
  }
  __syncthreads();

  const int ng = tid & 3, d = tid >> 2;
  float ar[25];
  {
    const float* basep = Aon + (size_t)(bid * 64 + d) * 100 + ng * 25;
#pragma unroll
    for (int q = 0; q < 25; ++q) ar[q] = basep[q];
  }
  float acc8[8];
#pragma unroll
  for (int bb = 0; bb < 8; ++bb) acc8[bb] = 0.f;
#pragma unroll
  for (int q = 0; q < 25; ++q) {
    int n = ng * 25 + q;
    float av = ar[q];
    float4 u0 = ld4(&uT[n * 8]);
    float4 u1 = ld4(&uT[n * 8 + 4]);
    acc8[0] += av * u0.x; acc8[1] += av * u0.y; acc8[2] += av * u0.z; acc8[3] += av * u0.w;
    acc8[4] += av * u1.x; acc8[5] += av * u1.y; acc8[6] += av * u1.z; acc8[7] += av * u1.w;
  }
  {
    float* pp = &part[(ng * 64 + d) * 8];
    *(float4*)pp = make_float4(acc8[0], acc8[1], acc8[2], acc8[3]);
    *(float4*)(pp + 4) = make_float4(acc8[4], acc8[5], acc8[6], acc8[7]);
  }
  __syncthreads();
  for (int o = tid; o < 512; o += 256) {
    int bp = o >> 6, d2 = o & 63;
    float s = aoo_s[d2] * kl_s[bp] * vl_s[bp * 64 + d2];
#pragma unroll
    for (int n2 = 0; n2 < 4; ++n2) s += part[(n2 * 64 + d2) * 8 + bp];
    h[(size_t)bp * 262144 + (size_t)bid * 64 + d2] = s;
  }
}

// ---------------------------------------------------------------- k_y
// y[bpt, b*64+d] = sum_{a,g} q[bpt, a*64+g] * h[bp, a, b, g, d]
__global__ __launch_bounds__(256) void k_y(const float* __restrict__ qw,
                                           const float* __restrict__ h,
                                           float* __restrict__ out) {
  __shared__ float qT[32 * 32];  // [kk][t]
  __shared__ float Hs[32 * 64];  // [kk][d]
  const int bid = blockIdx.x;    // bp*8 + b
  const int bp = bid >> 3, b = bid & 7;
  const int tid = threadIdx.x;
  const int r2 = tid >> 4, c2 = tid & 15;
  const size_t hbase = (size_t)bp * 262144 + (size_t)b * 4096;
  float acc[2][4];
#pragma unroll
  for (int i = 0; i < 2; ++i)
#pragma unroll
    for (int q = 0; q < 4; ++q) acc[i][q] = 0.f;

  for (int kc = 0; kc < 512; kc += 32) {
    {
      int t = tid & 31, kq = tid >> 5;  // kq 0..7
      float4 qv = ld4(qw + (size_t)(bp * 32 + t) * 512 + kc + kq * 4);
      qT[(kq * 4 + 0) * 32 + t] = qv.x;
      qT[(kq * 4 + 1) * 32 + t] = qv.y;
      qT[(kq * 4 + 2) * 32 + t] = qv.z;
      qT[(kq * 4 + 3) * 32 + t] = qv.w;
    }
#pragma unroll
    for (int i2 = 0; i2 < 2; ++i2) {
      int fid = i2 * 256 + tid;          // float4 id over 32x64
      int kk = fid >> 4, xq = (fid & 15) * 4;
      int row = kc + kk;
      int A = row >> 6, G = row & 63;
      float4 hv = ld4(h + hbase + (size_t)A * 32768 + (size_t)G * 64 + xq);
      *(float4*)&Hs[kk * 64 + xq] = hv;
    }
    __syncthreads();
#pragma unroll
    for (int kk = 0; kk < 32; ++kk) {
      float2 q2 = *(const float2*)&qT[kk * 32 + r2 * 2];
      float4 h4 = ld4(&Hs[kk * 64 + c2 * 4]);
      acc[0][0] += q2.x * h4.x; acc[0][1] += q2.x * h4.y; acc[0][2] += q2.x * h4.z; acc[0][3] += q2.x * h4.w;
      acc[1][0] += q2.y * h4.x; acc[1][1] += q2.y * h4.y; acc[1][2] += q2.y * h4.z; acc[1][3] += q2.y * h4.w;
    }
    __syncthreads();
  }
#pragma unroll
  for (int i = 0; i < 2; ++i) {
    float4 v = make_float4(acc[i][0], acc[i][1], acc[i][2], acc[i][3]);
    *(float4*)&out[(size_t)(bp * 32 + r2 * 2 + i) * 512 + b * 64 + c2 * 4] = v;
  }
}

// ---------------------------------------------------------------- launch
extern "C" void kernel_launch(void* const* d_in, const int* in_sizes, int n_in,
                              void* d_out, int out_size, void* d_ws, size_t ws_size,
                              hipStream_t stream) {
  const float* x   = (const float*)d_in[0];
  const float* K   = (const float*)d_in[1];
  const float* Q   = (const float*)d_in[2];
  const float* V   = (const float*)d_in[3];
  const float* Aoo = (const float*)d_in[4];
  const float* Ann = (const float*)d_in[5];
  const float* Aon = (const float*)d_in[6];
  const float* Ano = (const float*)d_in[7];
  float* out = (float*)d_out;

  float* ws  = (float*)d_ws;
  float* kw  = ws;                 // 131072
  float* qw  = kw + 131072;        // 131072
  float* vw  = qw + 131072;        // 131072
  float* tmp = vw + 131072;        // 13107200
  float* S   = tmp + 13107200;     // 25600
  float* u   = S + 25600;          // 800
  float* h   = u + 800;            // 2097152

  k_kqv<<<dim3(256), dim3(256), 0, stream>>>(x, K, Q, V, kw, qw, vw);
  k_tmp<<<dim3(800), dim3(256), 0, stream>>>(kw, Ano, tmp);
  k_S<<<dim3(256), dim3(128), 0, stream>>>(tmp, vw, S);
  k_scan<<<dim3(1), dim3(1024), 0, stream>>>(Ann, S, u);
  k_h<<<dim3(4096), dim3(256), 0, stream>>>(Aon, Aoo, kw, vw, u, h);
  k_y<<<dim3(64), dim3(256), 0, stream>>>(qw, h, out);
}

// Round 2
// 326.220 us; speedup vs baseline: 1.4075x; 1.4075x over previous
//
#include <hip/hip_runtime.h>

// GateLoopOperator, MI355X. Round 2: k_tmp -> bf16 MFMA GEMM (+ transpose/cvt pre-pass).
// B=4,P=2,T=32 (M=256 bpt), NLAT=8, NSP=64 (CX=512), NE=100.
//
// Pipeline:
//  k_cvt : BT[j][k] (bf16, 51200x512) = Ano reshaped [k=(c,x)][j=(k2,y,n)], transposed + cvt
//  k_kqv : k/q/v[m,C,X] f32 (+ kwb bf16 copy of k)
//  k_gemm: tmp[m][j] (bf16) = sum_k kwb[m][k] * BT[j][k]   (256x51200x512, MFMA 16x16x32)
//  k_S   : S[m,n] = sum_{ky} tmp[m][ky*100+n] * v[m][ky]
//  k_scan: u[bp,n] = S[bp,30] + sum_i Ann^(2^i) @ S[bp,29-i]  (serial, early-exit)
//  k_h   : h[bp,a,b,g,d] = Aoo*k_last*v_last + Aon . u
//  k_y   : y[bpt,b,d] = sum_{a,g} q[bpt,ag] * h[bp,a,b,g,d]

#define ANO_C_STR 3276800
#define ANO_K_STR 409600
#define ANO_X_STR 6400

typedef __attribute__((ext_vector_type(8))) short bf16x8;
typedef __attribute__((ext_vector_type(4))) float f32x4;
typedef __attribute__((ext_vector_type(8))) unsigned short u16x8;

__device__ __forceinline__ float4 ld4(const float* p) { return *(const float4*)p; }

__device__ __forceinline__ unsigned short f2bf(float f) {  // RNE
  unsigned u = __float_as_uint(f);
  unsigned r = (u + 0x7fffu + ((u >> 16) & 1u)) >> 16;
  return (unsigned short)r;
}
__device__ __forceinline__ float bf2f(unsigned short b) {
  return __uint_as_float(((unsigned)b) << 16);
}

// ---------------------------------------------------------------- k_cvt
// BT[j][k] = bf16(Ano[(k>>6), j/6400, k&63, (j%6400)]). 64x64 tile transpose via LDS.
__global__ __launch_bounds__(256) void k_cvt(const float* __restrict__ Ano,
                                             unsigned short* __restrict__ BT) {
  __shared__ float Ts[64 * 65];
  const int bid = blockIdx.x;  // jt*8 + kt
  const int j0 = (bid >> 3) * 64;
  const int k0 = (bid & 7) * 64;
  const int tid = threadIdx.x;
  const size_t cbase = (size_t)(k0 >> 6) * ANO_C_STR + (size_t)(j0 / 6400) * ANO_K_STR + (j0 % 6400);
#pragma unroll
  for (int i = 0; i < 4; ++i) {
    int f = i * 256 + tid;  // float4 id 0..1023 over 64x64
    int r = f >> 4, cq = f & 15;
    float4 v = ld4(Ano + cbase + (size_t)r * ANO_X_STR + cq * 4);
    float* d = &Ts[r * 65 + cq * 4];
    d[0] = v.x; d[1] = v.y; d[2] = v.z; d[3] = v.w;
  }
  __syncthreads();
#pragma unroll
  for (int i = 0; i < 2; ++i) {
    int jr = i * 32 + (tid >> 3);
    int kc8 = tid & 7;
    u16x8 o;
#pragma unroll
    for (int e = 0; e < 8; ++e) o[e] = f2bf(Ts[(kc8 * 8 + e) * 65 + jr]);
    *(u16x8*)&BT[(size_t)(j0 + jr) * 512 + k0 + kc8 * 8] = o;
  }
}

// ---------------------------------------------------------------- k_kqv
__global__ __launch_bounds__(256) void k_kqv(const float* __restrict__ X,
                                             const float* __restrict__ Km,
                                             const float* __restrict__ Qm,
                                             const float* __restrict__ Vm,
                                             float* __restrict__ kw,
                                             float* __restrict__ qw,
                                             float* __restrict__ vw,
                                             unsigned short* __restrict__ kwb) {
  __shared__ float xs[512];  // xs[x*8+c] = X[m, c, x]
  const int m = blockIdx.x;
  const int tid = threadIdx.x;
  for (int f = tid; f < 512; f += 256) {
    int c = f >> 6, x = f & 63;
    xs[(x << 3) | c] = X[m * 512 + f];
  }
  __syncthreads();
  const float4* xp = (const float4*)xs;
  for (int o = tid; o < 512; o += 256) {
    const int C = o >> 6, Xo = o & 63;
    const size_t base = (size_t)Xo * 4096 + (size_t)C * 512;
    const float4* kr = (const float4*)(Km + base);
    const float4* qr = (const float4*)(Qm + base);
    const float4* vr = (const float4*)(Vm + base);
    float ak = 0.f, aq = 0.f, av = 0.f;
#pragma unroll 4
    for (int j4 = 0; j4 < 128; ++j4) {
      float4 xv = xp[j4];
      float4 k4 = kr[j4];
      float4 q4 = qr[j4];
      float4 v4 = vr[j4];
      ak += k4.x * xv.x + k4.y * xv.y + k4.z * xv.z + k4.w * xv.w;
      aq += q4.x * xv.x + q4.y * xv.y + q4.z * xv.z + q4.w * xv.w;
      av += v4.x * xv.x + v4.y * xv.y + v4.z * xv.z + v4.w * xv.w;
    }
    kw[m * 512 + o] = ak;
    qw[m * 512 + o] = aq;
    vw[m * 512 + o] = av;
    kwb[m * 512 + o] = f2bf(ak);
  }
}

// ---------------------------------------------------------------- k_gemm
// tmp[256][51200] (bf16) = kwb[256][512] @ BT^T. BM=128, BN=128, BK=64.
// 4 waves in 2x2; per wave 64x64 = 4x4 frags of 16x16x32 MFMA.
// LDS linear [row][64] bf16, XOR chunk-swizzle via pre-swizzled global source
// (global_load_lds writes linearly; slot c8 holds global chunk c8^(row&7)).
__global__ __launch_bounds__(256) void k_gemm(const unsigned short* __restrict__ Abf,
                                              const unsigned short* __restrict__ BT,
                                              unsigned short* __restrict__ tmp) {
  __shared__ __align__(16) unsigned short Asm[128 * 64];
  __shared__ __align__(16) unsigned short Bsm[128 * 64];
  const int bid = blockIdx.x;  // 800; swizzled so the two mt of one jt share an XCD
  const int jt = ((bid >> 4) << 3) | (bid & 7);
  const int mt = (bid >> 3) & 1;
  const int m0 = mt * 128;
  const int j0 = jt * 128;
  const int tid = threadIdx.x;
  const int lane = tid & 63;
  const int w = tid >> 6;
  const int wm = w >> 1, wn = w & 1;

  f32x4 acc[4][4];
#pragma unroll
  for (int a = 0; a < 4; ++a)
#pragma unroll
    for (int b = 0; b < 4; ++b) acc[a][b] = (f32x4)(0.f);

  for (int kc = 0; kc < 512; kc += 64) {
#pragma unroll
    for (int cch = 0; cch < 4; ++cch) {
      int sid = cch * 256 + tid;  // slot 0..1023; dest byte = sid*16 (linear)
      int r = sid >> 3, c8 = sid & 7;
      int srcc = c8 ^ (r & 7);
      const unsigned short* ga = Abf + (size_t)(m0 + r) * 512 + kc + srcc * 8;
      __builtin_amdgcn_global_load_lds((const __attribute__((address_space(1))) unsigned int*)ga,
                                       (__attribute__((address_space(3))) unsigned int*)(&Asm[sid * 8]),
                                       16, 0, 0);
      const unsigned short* gb = BT + (size_t)(j0 + r) * 512 + kc + srcc * 8;
      __builtin_amdgcn_global_load_lds((const __attribute__((address_space(1))) unsigned int*)gb,
                                       (__attribute__((address_space(3))) unsigned int*)(&Bsm[sid * 8]),
                                       16, 0, 0);
    }
    __syncthreads();
#pragma unroll
    for (int ks = 0; ks < 2; ++ks) {
      bf16x8 af[4], bfr[4];
#pragma unroll
      for (int mf = 0; mf < 4; ++mf) {
        int r = wm * 64 + mf * 16 + (lane & 15);
        int slot = (ks * 4 + (lane >> 4)) ^ (r & 7);
        af[mf] = *(const bf16x8*)&Asm[r * 64 + slot * 8];
      }
#pragma unroll
      for (int nf = 0; nf < 4; ++nf) {
        int r = wn * 64 + nf * 16 + (lane & 15);
        int slot = (ks * 4 + (lane >> 4)) ^ (r & 7);
        bfr[nf] = *(const bf16x8*)&Bsm[r * 64 + slot * 8];
      }
#pragma unroll
      for (int mf = 0; mf < 4; ++mf)
#pragma unroll
        for (int nf = 0; nf < 4; ++nf)
          acc[mf][nf] = __builtin_amdgcn_mfma_f32_16x16x32_bf16(af[mf], bfr[nf], acc[mf][nf], 0, 0, 0);
    }
    __syncthreads();
  }
#pragma unroll
  for (int mf = 0; mf < 4; ++mf)
#pragma unroll
    for (int nf = 0; nf < 4; ++nf) {
      int col = j0 + wn * 64 + nf * 16 + (lane & 15);
#pragma unroll
      for (int r = 0; r < 4; ++r) {
        int row = m0 + wm * 64 + mf * 16 + (lane >> 4) * 4 + r;
        tmp[(size_t)row * 51200 + col] = f2bf(acc[mf][nf][r]);
      }
    }
}

// ---------------------------------------------------------------- k_S
__global__ __launch_bounds__(256) void k_S(const unsigned short* __restrict__ tmp,
                                           const float* __restrict__ vw,
                                           float* __restrict__ S) {
  __shared__ float vs[512];
  __shared__ float part[256];
  const int m = blockIdx.x;
  const int tid = threadIdx.x;
  for (int f = tid; f < 512; f += 256) vs[f] = vw[m * 512 + f];
  __syncthreads();
  const int half = tid >> 7, n = tid & 127;
  float acc = 0.f;
  if (n < 100) {
    const unsigned short* tr = tmp + (size_t)m * 51200 + n;
#pragma unroll 8
    for (int ky = half * 256; ky < half * 256 + 256; ++ky) acc += bf2f(tr[(size_t)ky * 100]) * vs[ky];
  }
  part[tid] = acc;
  __syncthreads();
  if (tid < 100) S[m * 100 + tid] = part[tid] + part[128 + tid];
}

// ---------------------------------------------------------------- k_scan
__global__ __launch_bounds__(1024) void k_scan(const float* __restrict__ Ann,
                                               const float* __restrict__ Sg,
                                               float* __restrict__ ug) {
  __shared__ float Abuf[10000];
  __shared__ float s_s[800];
  __shared__ float u_s[800];
  __shared__ float red[16];
  __shared__ int stopflag;
  const int tid = threadIdx.x;

  for (int f = tid; f < 10000; f += 1024) Abuf[f] = Ann[f];
  for (int f = tid; f < 800; f += 1024) {
    int bp = f / 100, n = f - bp * 100;
    u_s[f] = Sg[(bp * 32 + 30) * 100 + n];
  }
  const int ri = tid / 25;
  const int cj = tid - ri * 25;
  const bool sqact = (tid < 625);
  __syncthreads();

  for (int i = 0; i < 30; ++i) {
    const int t = 29 - i;
    for (int f = tid; f < 800; f += 1024) {
      int bp = f / 100, n = f - bp * 100;
      s_s[f] = Sg[(bp * 32 + t) * 100 + n];
    }
    __syncthreads();
    if (tid < 800) {
      int bp = tid / 100, n = tid - bp * 100;
      const float* Ar = &Abuf[n * 100];
      const float* sr = &s_s[bp * 100];
      float a0 = 0.f;
#pragma unroll
      for (int mm = 0; mm < 100; mm += 4) {
        float4 a4 = ld4(Ar + mm);
        float4 s4 = ld4(sr + mm);
        a0 += a4.x * s4.x + a4.y * s4.y + a4.z * s4.z + a4.w * s4.w;
      }
      u_s[tid] += a0;
    }
    if (i == 29) break;

    float acc2[4][4];
    float lmax = 0.f;
    if (sqact) {
#pragma unroll
      for (int a = 0; a < 4; ++a)
#pragma unroll
        for (int b = 0; b < 4; ++b) acc2[a][b] = 0.f;
      for (int mm = 0; mm < 100; mm += 4) {
        float av[4][4], bv[4][4];
#pragma unroll
        for (int ii = 0; ii < 4; ++ii)
          *(float4*)&av[ii][0] = ld4(&Abuf[(ri * 4 + ii) * 100 + mm]);
#pragma unroll
        for (int mi = 0; mi < 4; ++mi)
          *(float4*)&bv[mi][0] = ld4(&Abuf[(mm + mi) * 100 + cj * 4]);
#pragma unroll
        for (int ii = 0; ii < 4; ++ii)
#pragma unroll
          for (int mi = 0; mi < 4; ++mi)
#pragma unroll
            for (int qq = 0; qq < 4; ++qq) acc2[ii][qq] += av[ii][mi] * bv[mi][qq];
      }
    }
    __syncthreads();
    if (sqact) {
#pragma unroll
      for (int ii = 0; ii < 4; ++ii) {
        float4 wv = make_float4(acc2[ii][0], acc2[ii][1], acc2[ii][2], acc2[ii][3]);
        *(float4*)&Abuf[(ri * 4 + ii) * 100 + cj * 4] = wv;
        lmax = fmaxf(lmax, fmaxf(fmaxf(fabsf(wv.x), fabsf(wv.y)), fmaxf(fabsf(wv.z), fabsf(wv.w))));
      }
    }
#pragma unroll
    for (int off = 32; off > 0; off >>= 1) lmax = fmaxf(lmax, __shfl_down(lmax, off, 64));
    if ((tid & 63) == 0) red[tid >> 6] = lmax;
    __syncthreads();
    if (tid == 0) {
      float mx = 0.f;
      for (int wv = 0; wv < 16; ++wv) mx = fmaxf(mx, red[wv]);
      stopflag = (mx < 1e-28f) ? 1 : 0;
    }
    __syncthreads();
    if (stopflag) break;
  }
  __syncthreads();
  for (int f = tid; f < 800; f += 1024) ug[f] = u_s[f];
}

// ---------------------------------------------------------------- k_h
__global__ __launch_bounds__(256) void k_h(const float* __restrict__ Aon,
                                           const float* __restrict__ Aoo,
                                           const float* __restrict__ kw,
                                           const float* __restrict__ vw,
                                           const float* __restrict__ ug,
                                           float* __restrict__ h) {
  __shared__ float uT[100 * 8];
  __shared__ float aoo_s[64];
  __shared__ float kl_s[8];
  __shared__ float vl_s[8 * 64];
  __shared__ float part[4 * 64 * 8];
  const int bid = blockIdx.x;  // (a*8+b)*64+g
  const int g = bid & 63, b = (bid >> 6) & 7, a = bid >> 9;
  const int tid = threadIdx.x;

  for (int f = tid; f < 800; f += 256) {
    int n = f >> 3, bp = f & 7;
    uT[f] = ug[bp * 100 + n];
  }
  if (tid < 64) aoo_s[tid] = Aoo[(size_t)bid * 64 + tid];
  if (tid < 8) kl_s[tid] = kw[(size_t)(tid * 32 + 31) * 512 + a * 64 + g];
  for (int f = tid; f < 512; f += 256) {
    int bp = f >> 6, d = f & 63;
    vl_s[f] = vw[(size_t)(bp * 32 + 31) * 512 + b * 64 + d];
  }
  __syncthreads();

  const int ng = tid & 3, d = tid >> 2;
  float ar[25];
  {
    const float* basep = Aon + (size_t)(bid * 64 + d) * 100 + ng * 25;
#pragma unroll
    for (int q = 0; q < 25; ++q) ar[q] = basep[q];
  }
  float acc8[8];
#pragma unroll
  for (int bb = 0; bb < 8; ++bb) acc8[bb] = 0.f;
#pragma unroll
  for (int q = 0; q < 25; ++q) {
    int n = ng * 25 + q;
    float av = ar[q];
    float4 u0 = ld4(&uT[n * 8]);
    float4 u1 = ld4(&uT[n * 8 + 4]);
    acc8[0] += av * u0.x; acc8[1] += av * u0.y; acc8[2] += av * u0.z; acc8[3] += av * u0.w;
    acc8[4] += av * u1.x; acc8[5] += av * u1.y; acc8[6] += av * u1.z; acc8[7] += av * u1.w;
  }
  {
    float* pp = &part[(ng * 64 + d) * 8];
    *(float4*)pp = make_float4(acc8[0], acc8[1], acc8[2], acc8[3]);
    *(float4*)(pp + 4) = make_float4(acc8[4], acc8[5], acc8[6], acc8[7]);
  }
  __syncthreads();
  for (int o = tid; o < 512; o += 256) {
    int bp = o >> 6, d2 = o & 63;
    float s = aoo_s[d2] * kl_s[bp] * vl_s[bp * 64 + d2];
#pragma unroll
    for (int n2 = 0; n2 < 4; ++n2) s += part[(n2 * 64 + d2) * 8 + bp];
    h[(size_t)bp * 262144 + (size_t)bid * 64 + d2] = s;
  }
}

// ---------------------------------------------------------------- k_y
__global__ __launch_bounds__(256) void k_y(const float* __restrict__ qw,
                                           const float* __restrict__ h,
                                           float* __restrict__ out) {
  __shared__ float qT[32 * 32];
  __shared__ float Hs[32 * 64];
  const int bid = blockIdx.x;  // bp*8 + b
  const int bp = bid >> 3, b = bid & 7;
  const int tid = threadIdx.x;
  const int r2 = tid >> 4, c2 = tid & 15;
  const size_t hbase = (size_t)bp * 262144 + (size_t)b * 4096;
  float acc[2][4];
#pragma unroll
  for (int i = 0; i < 2; ++i)
#pragma unroll
    for (int q = 0; q < 4; ++q) acc[i][q] = 0.f;

  for (int kc = 0; kc < 512; kc += 32) {
    {
      int t = tid & 31, kq = tid >> 5;
      float4 qv = ld4(qw + (size_t)(bp * 32 + t) * 512 + kc + kq * 4);
      qT[(kq * 4 + 0) * 32 + t] = qv.x;
      qT[(kq * 4 + 1) * 32 + t] = qv.y;
      qT[(kq * 4 + 2) * 32 + t] = qv.z;
      qT[(kq * 4 + 3) * 32 + t] = qv.w;
    }
#pragma unroll
    for (int i2 = 0; i2 < 2; ++i2) {
      int fid = i2 * 256 + tid;
      int kk = fid >> 4, xq = (fid & 15) * 4;
      int row = kc + kk;
      int A = row >> 6, G = row & 63;
      float4 hv = ld4(h + hbase + (size_t)A * 32768 + (size_t)G * 64 + xq);
      *(float4*)&Hs[kk * 64 + xq] = hv;
    }
    __syncthreads();
#pragma unroll
    for (int kk = 0; kk < 32; ++kk) {
      float2 q2 = *(const float2*)&qT[kk * 32 + r2 * 2];
      float4 h4 = ld4(&Hs[kk * 64 + c2 * 4]);
      acc[0][0] += q2.x * h4.x; acc[0][1] += q2.x * h4.y; acc[0][2] += q2.x * h4.z; acc[0][3] += q2.x * h4.w;
      acc[1][0] += q2.y * h4.x; acc[1][1] += q2.y * h4.y; acc[1][2] += q2.y * h4.z; acc[1][3] += q2.y * h4.w;
    }
    __syncthreads();
  }
#pragma unroll
  for (int i = 0; i < 2; ++i) {
    float4 v = make_float4(acc[i][0], acc[i][1], acc[i][2], acc[i][3]);
    *(float4*)&out[(size_t)(bp * 32 + r2 * 2 + i) * 512 + b * 64 + c2 * 4] = v;
  }
}

// ---------------------------------------------------------------- launch
extern "C" void kernel_launch(void* const* d_in, const int* in_sizes, int n_in,
                              void* d_out, int out_size, void* d_ws, size_t ws_size,
                              hipStream_t stream) {
  const float* x   = (const float*)d_in[0];
  const float* K   = (const float*)d_in[1];
  const float* Q   = (const float*)d_in[2];
  const float* V   = (const float*)d_in[3];
  const float* Aoo = (const float*)d_in[4];
  const float* Ann = (const float*)d_in[5];
  const float* Aon = (const float*)d_in[6];
  const float* Ano = (const float*)d_in[7];
  float* out = (float*)d_out;

  float* ws = (float*)d_ws;
  // float-offset layout (concurrent peak ~81 MB):
  float* kw  = ws;                       // 131072
  float* qw  = kw + 131072;              // 131072
  float* vw  = qw + 131072;              // 131072
  unsigned short* kwb = (unsigned short*)(vw + 131072);   // 131072 u16 = 65536 f
  float* S   = ws + 458752;              // 25600
  float* u   = S + 25600;                // 800
  unsigned short* BT  = (unsigned short*)(ws + 485152);   // 26214400 u16 = 13107200 f
  unsigned short* tmp = (unsigned short*)(ws + 13592352); // 13107200 u16 = 6553600 f
  float* h   = ws + 485152;              // 2097152 f, aliases BT (dead after k_gemm)

  k_cvt<<<dim3(6400), dim3(256), 0, stream>>>(Ano, BT);
  k_kqv<<<dim3(256), dim3(256), 0, stream>>>(x, K, Q, V, kw, qw, vw, kwb);
  k_gemm<<<dim3(800), dim3(256), 0, stream>>>(kwb, BT, tmp);
  k_S<<<dim3(256), dim3(256), 0, stream>>>(tmp, vw, S);
  k_scan<<<dim3(1), dim3(1024), 0, stream>>>(Ann, S, u);
  k_h<<<dim3(4096), dim3(256), 0, stream>>>(Aon, Aoo, kw, vw, u, h);
  k_y<<<dim3(64), dim3(256), 0, stream>>>(qw, h, out);
}

// Round 3
// 272.975 us; speedup vs baseline: 1.6820x; 1.1951x over previous
//
#include <hip/hip_runtime.h>

// GateLoopOperator, MI355X. Round 3: k_kqv rewritten as latency-tolerant tiled f32 GEMM.
// B=4,P=2,T=32 (M=256 bpt), NLAT=8, NSP=64 (CX=512), NE=100.
//
// Pipeline:
//  k_cvt : BT[j][k] (bf16, 51200x512) = Ano reshaped [k=(c,x)][j=(k2,y,n)], transposed + cvt
//  k_xp  : xp[m][x*8+c] = x[m][c*64+x]  (permute so weight rows are contiguous)
//  k_kqv2: k/q/v[m,o] = xp[m,:] . W[r,:], o=((r&7)<<6)|(r>>3)  (96 blocks, 64x64 tiles)
//  k_gemm: tmp[m][j] (bf16) = sum_k kwb[m][k] * BT[j][k]   (256x51200x512, MFMA 16x16x32)
//  k_S   : S[m,n] = sum_{ky} tmp[m][ky*100+n] * v[m][ky]   (4-way ky split)
//  k_scan: u[bp,n] = S[bp,30] + sum_i Ann^(2^i) @ S[bp,29-i]  (serial, early-exit)
//  k_h   : h[bp,a,b,g,d] = Aoo*k_last*v_last + Aon . u
//  k_y   : y[bpt,b,d] = sum_{a,g} q[bpt,ag] * h[bp,a,b,g,d]

#define ANO_C_STR 3276800
#define ANO_K_STR 409600
#define ANO_X_STR 6400

typedef __attribute__((ext_vector_type(8))) short bf16x8;
typedef __attribute__((ext_vector_type(4))) float f32x4;
typedef __attribute__((ext_vector_type(8))) unsigned short u16x8;

__device__ __forceinline__ float4 ld4(const float* p) { return *(const float4*)p; }

__device__ __forceinline__ unsigned short f2bf(float f) {  // RNE
  unsigned u = __float_as_uint(f);
  unsigned r = (u + 0x7fffu + ((u >> 16) & 1u)) >> 16;
  return (unsigned short)r;
}
__device__ __forceinline__ float bf2f(unsigned short b) {
  return __uint_as_float(((unsigned)b) << 16);
}

// ---------------------------------------------------------------- k_cvt
__global__ __launch_bounds__(256) void k_cvt(const float* __restrict__ Ano,
                                             unsigned short* __restrict__ BT) {
  __shared__ float Ts[64 * 65];
  const int bid = blockIdx.x;  // jt*8 + kt
  const int j0 = (bid >> 3) * 64;
  const int k0 = (bid & 7) * 64;
  const int tid = threadIdx.x;
  const size_t cbase = (size_t)(k0 >> 6) * ANO_C_STR + (size_t)(j0 / 6400) * ANO_K_STR + (j0 % 6400);
#pragma unroll
  for (int i = 0; i < 4; ++i) {
    int f = i * 256 + tid;  // float4 id 0..1023 over 64x64
    int r = f >> 4, cq = f & 15;
    float4 v = ld4(Ano + cbase + (size_t)r * ANO_X_STR + cq * 4);
    float* d = &Ts[r * 65 + cq * 4];
    d[0] = v.x; d[1] = v.y; d[2] = v.z; d[3] = v.w;
  }
  __syncthreads();
#pragma unroll
  for (int i = 0; i < 2; ++i) {
    int jr = i * 32 + (tid >> 3);
    int kc8 = tid & 7;
    u16x8 o;
#pragma unroll
    for (int e = 0; e < 8; ++e) o[e] = f2bf(Ts[(kc8 * 8 + e) * 65 + jr]);
    *(u16x8*)&BT[(size_t)(j0 + jr) * 512 + k0 + kc8 * 8] = o;
  }
}

// ---------------------------------------------------------------- k_xp
// xp[m][f'] = x[m][(f'&7)*64 + (f'>>3)]
__global__ __launch_bounds__(256) void k_xp(const float* __restrict__ X,
                                            float* __restrict__ xp) {
  __shared__ float xs[512];
  const int m = blockIdx.x;
  const int tid = threadIdx.x;
  for (int f = tid; f < 512; f += 256) xs[f] = X[m * 512 + f];
  __syncthreads();
  for (int f = tid; f < 512; f += 256)
    xp[m * 512 + f] = xs[((f & 7) << 6) | (f >> 3)];
}

// ---------------------------------------------------------------- k_kqv2
// Out[m][o] = sum_f' xp[m][f'] * W[r][f'],  r row-major contiguous, o=((r&7)<<6)|(r>>3).
// grid (rt 0..7, mt 0..3, mat 0..2); 256 thr; 4x4 microtile; BK=32; reg-staged prefetch.
__global__ __launch_bounds__(256) void k_kqv2(const float* __restrict__ xp,
                                              const float* __restrict__ Km,
                                              const float* __restrict__ Qm,
                                              const float* __restrict__ Vm,
                                              float* __restrict__ kw,
                                              float* __restrict__ qw,
                                              float* __restrict__ vw,
                                              unsigned short* __restrict__ kwb) {
  __shared__ float xsT[32 * 65];  // [kk][mm] padded
  __shared__ float wsT[32 * 65];  // [kk][rr] padded
  const int rt = blockIdx.x, mt = blockIdx.y, mat = blockIdx.z;
  const int m0 = mt * 64, r0 = rt * 64;
  const float* W = (mat == 0) ? Km : ((mat == 1) ? Qm : Vm);
  float* Out = (mat == 0) ? kw : ((mat == 1) ? qw : vw);
  const int tid = threadIdx.x;
  const int ty = tid >> 4, tx = tid & 15;
  const int row = tid >> 3, colq = tid & 7;  // for staging: row 0..31 (i gives +32)

  float4 rx[2], rw[2];
#pragma unroll
  for (int i = 0; i < 2; ++i) {
    rx[i] = ld4(xp + (size_t)(m0 + i * 32 + row) * 512 + colq * 4);
    rw[i] = ld4(W + (size_t)(r0 + i * 32 + row) * 512 + colq * 4);
  }

  float acc[4][4];
#pragma unroll
  for (int a = 0; a < 4; ++a)
#pragma unroll
    for (int b = 0; b < 4; ++b) acc[a][b] = 0.f;

  for (int s = 0; s < 16; ++s) {
    __syncthreads();
#pragma unroll
    for (int i = 0; i < 2; ++i) {
      int rr = i * 32 + row;
      xsT[(colq * 4 + 0) * 65 + rr] = rx[i].x;
      xsT[(colq * 4 + 1) * 65 + rr] = rx[i].y;
      xsT[(colq * 4 + 2) * 65 + rr] = rx[i].z;
      xsT[(colq * 4 + 3) * 65 + rr] = rx[i].w;
      wsT[(colq * 4 + 0) * 65 + rr] = rw[i].x;
      wsT[(colq * 4 + 1) * 65 + rr] = rw[i].y;
      wsT[(colq * 4 + 2) * 65 + rr] = rw[i].z;
      wsT[(colq * 4 + 3) * 65 + rr] = rw[i].w;
    }
    __syncthreads();
    if (s < 15) {
      int kc = (s + 1) * 32;
#pragma unroll
      for (int i = 0; i < 2; ++i) {
        rx[i] = ld4(xp + (size_t)(m0 + i * 32 + row) * 512 + kc + colq * 4);
        rw[i] = ld4(W + (size_t)(r0 + i * 32 + row) * 512 + kc + colq * 4);
      }
    }
#pragma unroll 4
    for (int kk = 0; kk < 32; ++kk) {
      float xa[4], wa[4];
      *(float4*)&xa[0] = ld4(&xsT[kk * 65 + ty * 4]);
      *(float4*)&wa[0] = ld4(&wsT[kk * 65 + tx * 4]);
#pragma unroll
      for (int a = 0; a < 4; ++a)
#pragma unroll
        for (int b = 0; b < 4; ++b) acc[a][b] += xa[a] * wa[b];
    }
  }

#pragma unroll
  for (int b = 0; b < 4; ++b) {
    int r = r0 + tx * 4 + b;
    int o = ((r & 7) << 6) | (r >> 3);
#pragma unroll
    for (int a = 0; a < 4; ++a) {
      int mr = m0 + ty * 4 + a;
      Out[(size_t)mr * 512 + o] = acc[a][b];
      if (mat == 0) kwb[(size_t)mr * 512 + o] = f2bf(acc[a][b]);
    }
  }
}

// ---------------------------------------------------------------- k_gemm
// tmp[256][51200] (bf16) = kwb[256][512] @ BT^T. BM=128, BN=128, BK=64.
__global__ __launch_bounds__(256) void k_gemm(const unsigned short* __restrict__ Abf,
                                              const unsigned short* __restrict__ BT,
                                              unsigned short* __restrict__ tmp) {
  __shared__ __align__(16) unsigned short Asm[128 * 64];
  __shared__ __align__(16) unsigned short Bsm[128 * 64];
  const int bid = blockIdx.x;
  const int jt = ((bid >> 4) << 3) | (bid & 7);
  const int mt = (bid >> 3) & 1;
  const int m0 = mt * 128;
  const int j0 = jt * 128;
  const int tid = threadIdx.x;
  const int lane = tid & 63;
  const int w = tid >> 6;
  const int wm = w >> 1, wn = w & 1;

  f32x4 acc[4][4];
#pragma unroll
  for (int a = 0; a < 4; ++a)
#pragma unroll
    for (int b = 0; b < 4; ++b) acc[a][b] = (f32x4)(0.f);

  for (int kc = 0; kc < 512; kc += 64) {
#pragma unroll
    for (int cch = 0; cch < 4; ++cch) {
      int sid = cch * 256 + tid;
      int r = sid >> 3, c8 = sid & 7;
      int srcc = c8 ^ (r & 7);
      const unsigned short* ga = Abf + (size_t)(m0 + r) * 512 + kc + srcc * 8;
      __builtin_amdgcn_global_load_lds((const __attribute__((address_space(1))) unsigned int*)ga,
                                       (__attribute__((address_space(3))) unsigned int*)(&Asm[sid * 8]),
                                       16, 0, 0);
      const unsigned short* gb = BT + (size_t)(j0 + r) * 512 + kc + srcc * 8;
      __builtin_amdgcn_global_load_lds((const __attribute__((address_space(1))) unsigned int*)gb,
                                       (__attribute__((address_space(3))) unsigned int*)(&Bsm[sid * 8]),
                                       16, 0, 0);
    }
    __syncthreads();
#pragma unroll
    for (int ks = 0; ks < 2; ++ks) {
      bf16x8 af[4], bfr[4];
#pragma unroll
      for (int mf = 0; mf < 4; ++mf) {
        int r = wm * 64 + mf * 16 + (lane & 15);
        int slot = (ks * 4 + (lane >> 4)) ^ (r & 7);
        af[mf] = *(const bf16x8*)&Asm[r * 64 + slot * 8];
      }
#pragma unroll
      for (int nf = 0; nf < 4; ++nf) {
        int r = wn * 64 + nf * 16 + (lane & 15);
        int slot = (ks * 4 + (lane >> 4)) ^ (r & 7);
        bfr[nf] = *(const bf16x8*)&Bsm[r * 64 + slot * 8];
      }
#pragma unroll
      for (int mf = 0; mf < 4; ++mf)
#pragma unroll
        for (int nf = 0; nf < 4; ++nf)
          acc[mf][nf] = __builtin_amdgcn_mfma_f32_16x16x32_bf16(af[mf], bfr[nf], acc[mf][nf], 0, 0, 0);
    }
    __syncthreads();
  }
#pragma unroll
  for (int mf = 0; mf < 4; ++mf)
#pragma unroll
    for (int nf = 0; nf < 4; ++nf) {
      int col = j0 + wn * 64 + nf * 16 + (lane & 15);
#pragma unroll
      for (int r = 0; r < 4; ++r) {
        int rrow = m0 + wm * 64 + mf * 16 + (lane >> 4) * 4 + r;
        tmp[(size_t)rrow * 51200 + col] = f2bf(acc[mf][nf][r]);
      }
    }
}

// ---------------------------------------------------------------- k_S
__global__ __launch_bounds__(512) void k_S(const unsigned short* __restrict__ tmp,
                                           const float* __restrict__ vw,
                                           float* __restrict__ S) {
  __shared__ float vs[512];
  __shared__ float part[512];
  const int m = blockIdx.x;
  const int tid = threadIdx.x;
  if (tid < 512) vs[tid] = vw[m * 512 + tid];
  __syncthreads();
  const int quad = tid >> 7, n = tid & 127;
  float acc = 0.f;
  if (n < 100) {
    const unsigned short* tr = tmp + (size_t)m * 51200 + n;
#pragma unroll 8
    for (int ky = quad * 128; ky < quad * 128 + 128; ++ky) acc += bf2f(tr[(size_t)ky * 100]) * vs[ky];
  }
  part[tid] = acc;
  __syncthreads();
  if (tid < 100)
    S[m * 100 + tid] = part[tid] + part[128 + tid] + part[256 + tid] + part[384 + tid];
}

// ---------------------------------------------------------------- k_scan
__global__ __launch_bounds__(1024) void k_scan(const float* __restrict__ Ann,
                                               const float* __restrict__ Sg,
                                               float* __restrict__ ug) {
  __shared__ float Abuf[10000];
  __shared__ float s_s[800];
  __shared__ float u_s[800];
  __shared__ float red[16];
  __shared__ int stopflag;
  const int tid = threadIdx.x;

  for (int f = tid; f < 10000; f += 1024) Abuf[f] = Ann[f];
  for (int f = tid; f < 800; f += 1024) {
    int bp = f / 100, n = f - bp * 100;
    u_s[f] = Sg[(bp * 32 + 30) * 100 + n];
  }
  const int ri = tid / 25;
  const int cj = tid - ri * 25;
  const bool sqact = (tid < 625);
  __syncthreads();

  for (int i = 0; i < 30; ++i) {
    const int t = 29 - i;
    for (int f = tid; f < 800; f += 1024) {
      int bp = f / 100, n = f - bp * 100;
      s_s[f] = Sg[(bp * 32 + t) * 100 + n];
    }
    __syncthreads();
    if (tid < 800) {
      int bp = tid / 100, n = tid - bp * 100;
      const float* Ar = &Abuf[n * 100];
      const float* sr = &s_s[bp * 100];
      float a0 = 0.f;
#pragma unroll
      for (int mm = 0; mm < 100; mm += 4) {
        float4 a4 = ld4(Ar + mm);
        float4 s4 = ld4(sr + mm);
        a0 += a4.x * s4.x + a4.y * s4.y + a4.z * s4.z + a4.w * s4.w;
      }
      u_s[tid] += a0;
    }
    if (i == 29) break;

    float acc2[4][4];
    float lmax = 0.f;
    if (sqact) {
#pragma unroll
      for (int a = 0; a < 4; ++a)
#pragma unroll
        for (int b = 0; b < 4; ++b) acc2[a][b] = 0.f;
      for (int mm = 0; mm < 100; mm += 4) {
        float av[4][4], bv[4][4];
#pragma unroll
        for (int ii = 0; ii < 4; ++ii)
          *(float4*)&av[ii][0] = ld4(&Abuf[(ri * 4 + ii) * 100 + mm]);
#pragma unroll
        for (int mi = 0; mi < 4; ++mi)
          *(float4*)&bv[mi][0] = ld4(&Abuf[(mm + mi) * 100 + cj * 4]);
#pragma unroll
        for (int ii = 0; ii < 4; ++ii)
#pragma unroll
          for (int mi = 0; mi < 4; ++mi)
#pragma unroll
            for (int qq = 0; qq < 4; ++qq) acc2[ii][qq] += av[ii][mi] * bv[mi][qq];
      }
    }
    __syncthreads();
    if (sqact) {
#pragma unroll
      for (int ii = 0; ii < 4; ++ii) {
        float4 wv = make_float4(acc2[ii][0], acc2[ii][1], acc2[ii][2], acc2[ii][3]);
        *(float4*)&Abuf[(ri * 4 + ii) * 100 + cj * 4] = wv;
        lmax = fmaxf(lmax, fmaxf(fmaxf(fabsf(wv.x), fabsf(wv.y)), fmaxf(fabsf(wv.z), fabsf(wv.w))));
      }
    }
#pragma unroll
    for (int off = 32; off > 0; off >>= 1) lmax = fmaxf(lmax, __shfl_down(lmax, off, 64));
    if ((tid & 63) == 0) red[tid >> 6] = lmax;
    __syncthreads();
    if (tid == 0) {
      float mx = 0.f;
      for (int wv = 0; wv < 16; ++wv) mx = fmaxf(mx, red[wv]);
      stopflag = (mx < 1e-28f) ? 1 : 0;
    }
    __syncthreads();
    if (stopflag) break;
  }
  __syncthreads();
  for (int f = tid; f < 800; f += 1024) ug[f] = u_s[f];
}

// ---------------------------------------------------------------- k_h
__global__ __launch_bounds__(256) void k_h(const float* __restrict__ Aon,
                                           const float* __restrict__ Aoo,
                                           const float* __restrict__ kw,
                                           const float* __restrict__ vw,
                                           const float* __restrict__ ug,
                                           float* __restrict__ h) {
  __shared__ float uT[100 * 8];
  __shared__ float aoo_s[64];
  __shared__ float kl_s[8];
  __shared__ float vl_s[8 * 64];
  __shared__ float part[4 * 64 * 8];
  const int bid = blockIdx.x;  // (a*8+b)*64+g
  const int g = bid & 63, b = (bid >> 6) & 7, a = bid >> 9;
  const int tid = threadIdx.x;

  for (int f = tid; f < 800; f += 256) {
    int n = f >> 3, bp = f & 7;
    uT[f] = ug[bp * 100 + n];
  }
  if (tid < 64) aoo_s[tid] = Aoo[(size_t)bid * 64 + tid];
  if (tid < 8) kl_s[tid] = kw[(size_t)(tid * 32 + 31) * 512 + a * 64 + g];
  for (int f = tid; f < 512; f += 256) {
    int bp = f >> 6, d = f & 63;
    vl_s[f] = vw[(size_t)(bp * 32 + 31) * 512 + b * 64 + d];
  }
  __syncthreads();

  const int ng = tid & 3, d = tid >> 2;
  float ar[25];
  {
    const float* basep = Aon + (size_t)(bid * 64 + d) * 100 + ng * 25;
#pragma unroll
    for (int q = 0; q < 25; ++q) ar[q] = basep[q];
  }
  float acc8[8];
#pragma unroll
  for (int bb = 0; bb < 8; ++bb) acc8[bb] = 0.f;
#pragma unroll
  for (int q = 0; q < 25; ++q) {
    int n = ng * 25 + q;
    float av = ar[q];
    float4 u0 = ld4(&uT[n * 8]);
    float4 u1 = ld4(&uT[n * 8 + 4]);
    acc8[0] += av * u0.x; acc8[1] += av * u0.y; acc8[2] += av * u0.z; acc8[3] += av * u0.w;
    acc8[4] += av * u1.x; acc8[5] += av * u1.y; acc8[6] += av * u1.z; acc8[7] += av * u1.w;
  }
  {
    float* pp = &part[(ng * 64 + d) * 8];
    *(float4*)pp = make_float4(acc8[0], acc8[1], acc8[2], acc8[3]);
    *(float4*)(pp + 4) = make_float4(acc8[4], acc8[5], acc8[6], acc8[7]);
  }
  __syncthreads();
  for (int o = tid; o < 512; o += 256) {
    int bp = o >> 6, d2 = o & 63;
    float s = aoo_s[d2] * kl_s[bp] * vl_s[bp * 64 + d2];
#pragma unroll
    for (int n2 = 0; n2 < 4; ++n2) s += part[(n2 * 64 + d2) * 8 + bp];
    h[(size_t)bp * 262144 + (size_t)bid * 64 + d2] = s;
  }
}

// ---------------------------------------------------------------- k_y
__global__ __launch_bounds__(256) void k_y(const float* __restrict__ qw,
                                           const float* __restrict__ h,
                                           float* __restrict__ out) {
  __shared__ float qT[32 * 32];
  __shared__ float Hs[32 * 64];
  const int bid = blockIdx.x;  // bp*8 + b
  const int bp = bid >> 3, b = bid & 7;
  const int tid = threadIdx.x;
  const int r2 = tid >> 4, c2 = tid & 15;
  const size_t hbase = (size_t)bp * 262144 + (size_t)b * 4096;
  float acc[2][4];
#pragma unroll
  for (int i = 0; i < 2; ++i)
#pragma unroll
    for (int q = 0; q < 4; ++q) acc[i][q] = 0.f;

  for (int kc = 0; kc < 512; kc += 32) {
    {
      int t = tid & 31, kq = tid >> 5;
      float4 qv = ld4(qw + (size_t)(bp * 32 + t) * 512 + kc + kq * 4);
      qT[(kq * 4 + 0) * 32 + t] = qv.x;
      qT[(kq * 4 + 1) * 32 + t] = qv.y;
      qT[(kq * 4 + 2) * 32 + t] = qv.z;
      qT[(kq * 4 + 3) * 32 + t] = qv.w;
    }
#pragma unroll
    for (int i2 = 0; i2 < 2; ++i2) {
      int fid = i2 * 256 + tid;
      int kk = fid >> 4, xq = (fid & 15) * 4;
      int row = kc + kk;
      int A = row >> 6, G = row & 63;
      float4 hv = ld4(h + hbase + (size_t)A * 32768 + (size_t)G * 64 + xq);
      *(float4*)&Hs[kk * 64 + xq] = hv;
    }
    __syncthreads();
#pragma unroll
    for (int kk = 0; kk < 32; ++kk) {
      float2 q2 = *(const float2*)&qT[kk * 32 + r2 * 2];
      float4 h4 = ld4(&Hs[kk * 64 + c2 * 4]);
      acc[0][0] += q2.x * h4.x; acc[0][1] += q2.x * h4.y; acc[0][2] += q2.x * h4.z; acc[0][3] += q2.x * h4.w;
      acc[1][0] += q2.y * h4.x; acc[1][1] += q2.y * h4.y; acc[1][2] += q2.y * h4.z; acc[1][3] += q2.y * h4.w;
    }
    __syncthreads();
  }
#pragma unroll
  for (int i = 0; i < 2; ++i) {
    float4 v = make_float4(acc[i][0], acc[i][1], acc[i][2], acc[i][3]);
    *(float4*)&out[(size_t)(bp * 32 + r2 * 2 + i) * 512 + b * 64 + c2 * 4] = v;
  }
}

// ---------------------------------------------------------------- launch
extern "C" void kernel_launch(void* const* d_in, const int* in_sizes, int n_in,
                              void* d_out, int out_size, void* d_ws, size_t ws_size,
                              hipStream_t stream) {
  const float* x   = (const float*)d_in[0];
  const float* K   = (const float*)d_in[1];
  const float* Q   = (const float*)d_in[2];
  const float* V   = (const float*)d_in[3];
  const float* Aoo = (const float*)d_in[4];
  const float* Ann = (const float*)d_in[5];
  const float* Aon = (const float*)d_in[6];
  const float* Ano = (const float*)d_in[7];
  float* out = (float*)d_out;

  float* ws = (float*)d_ws;
  float* kw  = ws;                       // 131072
  float* qw  = kw + 131072;              // 131072
  float* vw  = qw + 131072;              // 131072
  unsigned short* kwb = (unsigned short*)(vw + 131072);   // 65536 f
  float* S   = ws + 458752;              // 25600
  float* u   = S + 25600;                // 800
  unsigned short* BT  = (unsigned short*)(ws + 485152);   // 13107200 f
  unsigned short* tmp = (unsigned short*)(ws + 13592352); // 6553600 f
  float* h   = ws + 485152;              // 2097152 f, aliases BT (dead after k_gemm)
  float* xp  = ws + 13592352;            // 131072 f, aliases tmp region (dead before k_gemm)

  k_cvt<<<dim3(6400), dim3(256), 0, stream>>>(Ano, BT);
  k_xp<<<dim3(256), dim3(256), 0, stream>>>(x, xp);
  k_kqv2<<<dim3(8, 4, 3), dim3(256), 0, stream>>>(xp, K, Q, V, kw, qw, vw, kwb);
  k_gemm<<<dim3(800), dim3(256), 0, stream>>>(kwb, BT, tmp);
  k_S<<<dim3(256), dim3(512), 0, stream>>>(tmp, vw, S);
  k_scan<<<dim3(1), dim3(1024), 0, stream>>>(Ann, S, u);
  k_h<<<dim3(4096), dim3(256), 0, stream>>>(Aon, Aoo, kw, vw, u, h);
  k_y<<<dim3(64), dim3(256), 0, stream>>>(qw, h, out);
}

// Round 4
// 210.714 us; speedup vs baseline: 2.1790x; 1.2955x over previous
//
#include <hip/hip_runtime.h>

// GateLoopOperator, MI355X. Round 4:
//  - kqv via split-bf16 MFMA GEMM (x_hi*W_hi + x_hi*W_lo + x_lo*W_hi, K=1536) -> f32-quality
//  - k_cvt fused into k_gemm2 (B staged from f32 Ano, cvt in-register, swizzled ds_write)
//
// Pipeline:
//  k_prep : A2[m][1536] bf16 = [hi(xp) | hi(xp) | lo(xp)], xp[m][x*8+c]=x[m][c*64+x]
//  k_cvtW : Bw[j=mat*512+o][1536] bf16 = [hi(W_mat[r(o)]) | lo | hi], r(o)=((o&63)<<3)|(o>>6)
//  k_kqv3 : kqvF[mat][m][o] f32 = A2 @ Bw^T  (MFMA, M=256,N=1536,K=1536) + kwb bf16
//  k_gemm2: tmp[m][j] bf16 = kwb[m][:] . Ano[:, j]  (M=256,J=51200,K=512; B from f32 Ano)
//  k_S    : S[m,n] = sum_{ky} tmp[m][ky*100+n] * v[m][ky]
//  k_scan : u[bp,n] = S[bp,30] + sum_i Ann^(2^i) @ S[bp,29-i]  (serial, early-exit)
//  k_h    : h[bp,a,b,g,d] = Aoo*k_last*v_last + Aon . u
//  k_y    : y[bpt,b,d] = sum_{a,g} q[bpt,ag] * h[bp,a,b,g,d]

#define ANO_C_STR 3276800
#define ANO_K_STR 409600
#define ANO_X_STR 6400

typedef __attribute__((ext_vector_type(8))) short bf16x8;
typedef __attribute__((ext_vector_type(4))) float f32x4;
typedef __attribute__((ext_vector_type(4))) unsigned short u16x4;

__device__ __forceinline__ float4 ld4(const float* p) { return *(const float4*)p; }

__device__ __forceinline__ unsigned short f2bf(float f) {  // RNE
  unsigned u = __float_as_uint(f);
  unsigned r = (u + 0x7fffu + ((u >> 16) & 1u)) >> 16;
  return (unsigned short)r;
}
__device__ __forceinline__ float bf2f(unsigned short b) {
  return __uint_as_float(((unsigned)b) << 16);
}

// ---------------------------------------------------------------- k_prep
// A2[m][f]=hi(xp), A2[m][512+f]=hi(xp), A2[m][1024+f]=lo(xp); xp[f]=x[m][(f&7)*64+(f>>3)]
__global__ __launch_bounds__(256) void k_prep(const float* __restrict__ X,
                                              unsigned short* __restrict__ A2) {
  __shared__ float xs[512];
  const int m = blockIdx.x;
  const int tid = threadIdx.x;
  for (int f = tid; f < 512; f += 256) xs[f] = X[m * 512 + f];
  __syncthreads();
  for (int f = tid; f < 512; f += 256) {
    float v = xs[((f & 7) << 6) | (f >> 3)];
    unsigned short hi = f2bf(v);
    unsigned short lo = f2bf(v - bf2f(hi));
    A2[(size_t)m * 1536 + f] = hi;
    A2[(size_t)m * 1536 + 512 + f] = hi;
    A2[(size_t)m * 1536 + 1024 + f] = lo;
  }
}

// ---------------------------------------------------------------- k_cvtW
__global__ __launch_bounds__(128) void k_cvtW(const float* __restrict__ Km,
                                              const float* __restrict__ Qm,
                                              const float* __restrict__ Vm,
                                              unsigned short* __restrict__ Bw) {
  const int j = blockIdx.x;  // mat*512 + o
  const int mat = j >> 9, o = j & 511;
  const int r = ((o & 63) << 3) | (o >> 6);
  const float* W = ((mat == 0) ? Km : ((mat == 1) ? Qm : Vm)) + (size_t)r * 512;
  const int tid = threadIdx.x;
  float4 v = ld4(W + tid * 4);
  u16x4 hi, lo;
  float vv[4] = {v.x, v.y, v.z, v.w};
#pragma unroll
  for (int e = 0; e < 4; ++e) {
    hi[e] = f2bf(vv[e]);
    lo[e] = f2bf(vv[e] - bf2f(hi[e]));
  }
  *(u16x4*)&Bw[(size_t)j * 1536 + tid * 4] = hi;
  *(u16x4*)&Bw[(size_t)j * 1536 + 512 + tid * 4] = lo;
  *(u16x4*)&Bw[(size_t)j * 1536 + 1024 + tid * 4] = hi;
}

// ---------------------------------------------------------------- k_kqv3
// kqvF[mat*131072 + m*512 + o] = sum_k A2[m][k]*Bw[mat*512+o][k]. BM=BN=128, BK=64, grid 24.
__global__ __launch_bounds__(256) void k_kqv3(const unsigned short* __restrict__ A2,
                                              const unsigned short* __restrict__ Bw,
                                              float* __restrict__ kqvF,
                                              unsigned short* __restrict__ kwb) {
  __shared__ __align__(16) unsigned short Asm[128 * 64];
  __shared__ __align__(16) unsigned short Bsm[128 * 64];
  const int bid = blockIdx.x;  // 24
  const int mt = bid & 1, jt = bid >> 1;
  const int m0 = mt * 128, j0 = jt * 128;
  const int tid = threadIdx.x;
  const int lane = tid & 63;
  const int w = tid >> 6;
  const int wm = w >> 1, wn = w & 1;

  f32x4 acc[4][4];
#pragma unroll
  for (int a = 0; a < 4; ++a)
#pragma unroll
    for (int b = 0; b < 4; ++b) acc[a][b] = (f32x4)(0.f);

  for (int kc = 0; kc < 1536; kc += 64) {
#pragma unroll
    for (int cch = 0; cch < 4; ++cch) {
      int sid = cch * 256 + tid;
      int r = sid >> 3, c8 = sid & 7;
      int srcc = c8 ^ (r & 7);
      const unsigned short* ga = A2 + (size_t)(m0 + r) * 1536 + kc + srcc * 8;
      __builtin_amdgcn_global_load_lds((const __attribute__((address_space(1))) unsigned int*)ga,
                                       (__attribute__((address_space(3))) unsigned int*)(&Asm[sid * 8]),
                                       16, 0, 0);
      const unsigned short* gb = Bw + (size_t)(j0 + r) * 1536 + kc + srcc * 8;
      __builtin_amdgcn_global_load_lds((const __attribute__((address_space(1))) unsigned int*)gb,
                                       (__attribute__((address_space(3))) unsigned int*)(&Bsm[sid * 8]),
                                       16, 0, 0);
    }
    __syncthreads();
#pragma unroll
    for (int ks = 0; ks < 2; ++ks) {
      bf16x8 af[4], bfr[4];
#pragma unroll
      for (int mf = 0; mf < 4; ++mf) {
        int r = wm * 64 + mf * 16 + (lane & 15);
        int slot = (ks * 4 + (lane >> 4)) ^ (r & 7);
        af[mf] = *(const bf16x8*)&Asm[r * 64 + slot * 8];
      }
#pragma unroll
      for (int nf = 0; nf < 4; ++nf) {
        int r = wn * 64 + nf * 16 + (lane & 15);
        int slot = (ks * 4 + (lane >> 4)) ^ (r & 7);
        bfr[nf] = *(const bf16x8*)&Bsm[r * 64 + slot * 8];
      }
#pragma unroll
      for (int mf = 0; mf < 4; ++mf)
#pragma unroll
        for (int nf = 0; nf < 4; ++nf)
          acc[mf][nf] = __builtin_amdgcn_mfma_f32_16x16x32_bf16(af[mf], bfr[nf], acc[mf][nf], 0, 0, 0);
    }
    __syncthreads();
  }
#pragma unroll
  for (int mf = 0; mf < 4; ++mf)
#pragma unroll
    for (int nf = 0; nf < 4; ++nf) {
      int col = j0 + wn * 64 + nf * 16 + (lane & 15);
      int mat = col >> 9, o = col & 511;
      float* Outp = kqvF + (size_t)mat * 131072;
#pragma unroll
      for (int r = 0; r < 4; ++r) {
        int row = m0 + wm * 64 + mf * 16 + (lane >> 4) * 4 + r;
        float val = acc[mf][nf][r];
        Outp[(size_t)row * 512 + o] = val;
        if (mat == 0) kwb[(size_t)row * 512 + o] = f2bf(val);
      }
    }
}

// ---------------------------------------------------------------- k_gemm2
// tmp[256][51200] bf16 = kwb @ AnoMat. B staged from f32 Ano in-kernel.
// Bsm u32 word (j, kpair a) at j*32 + (a ^ ((j&7)<<2)); 16B read slot = g^(j&7) (same as A path).
__global__ __launch_bounds__(256) void k_gemm2(const unsigned short* __restrict__ Abf,
                                               const float* __restrict__ Ano,
                                               unsigned short* __restrict__ tmp) {
  __shared__ __align__(16) unsigned short Asm[128 * 64];
  __shared__ __align__(16) unsigned short Bsm[128 * 64];
  const int bid = blockIdx.x;  // 800; bid and bid+8 share jt -> same XCD L2 reuse of Ano
  const int jt = ((bid >> 4) << 3) | (bid & 7);
  const int mt = (bid >> 3) & 1;
  const int m0 = mt * 128;
  const int j0 = jt * 128;
  const int tid = threadIdx.x;
  const int lane = tid & 63;
  const int w = tid >> 6;
  const int wm = w >> 1, wn = w & 1;
  const int k2 = j0 / 6400;
  const int jloc = j0 - k2 * 6400;
  const float* anoBase = Ano + (size_t)k2 * ANO_K_STR + jloc;
  const int ta = tid & 31;      // x-pair index
  const int tb0 = tid >> 5;     // 0..7

  f32x4 acc[4][4];
#pragma unroll
  for (int a = 0; a < 4; ++a)
#pragma unroll
    for (int b = 0; b < 4; ++b) acc[a][b] = (f32x4)(0.f);

  for (int kc = 0; kc < 512; kc += 64) {
    const int c = kc >> 6;
    const float* anoC = anoBase + (size_t)c * ANO_C_STR;
    // B tile 64x(128 f32) -> regs
    float4 bx0[4], bx1[4];
#pragma unroll
    for (int it = 0; it < 4; ++it) {
      int b = it * 8 + tb0;
      const float* p0 = anoC + (size_t)(2 * ta) * ANO_X_STR + b * 4;
      bx0[it] = ld4(p0);
      bx1[it] = ld4(p0 + ANO_X_STR);
    }
    // A tile via global_load_lds (source-swizzled)
#pragma unroll
    for (int cch = 0; cch < 4; ++cch) {
      int sid = cch * 256 + tid;
      int r = sid >> 3, c8 = sid & 7;
      int srcc = c8 ^ (r & 7);
      const unsigned short* ga = Abf + (size_t)(m0 + r) * 512 + kc + srcc * 8;
      __builtin_amdgcn_global_load_lds((const __attribute__((address_space(1))) unsigned int*)ga,
                                       (__attribute__((address_space(3))) unsigned int*)(&Asm[sid * 8]),
                                       16, 0, 0);
    }
    // cvt + pack + swizzled ds_write of B
    unsigned* bdst = (unsigned*)Bsm;
#pragma unroll
    for (int it = 0; it < 4; ++it) {
      int b = it * 8 + tb0;
      float v0[4] = {bx0[it].x, bx0[it].y, bx0[it].z, bx0[it].w};
      float v1[4] = {bx1[it].x, bx1[it].y, bx1[it].z, bx1[it].w};
#pragma unroll
      for (int e = 0; e < 4; ++e) {
        int j = 4 * b + e;
        unsigned pk = (unsigned)f2bf(v0[e]) | ((unsigned)f2bf(v1[e]) << 16);
        bdst[j * 32 + (ta ^ ((j & 7) << 2))] = pk;
      }
    }
    __syncthreads();
#pragma unroll
    for (int ks = 0; ks < 2; ++ks) {
      bf16x8 af[4], bfr[4];
#pragma unroll
      for (int mf = 0; mf < 4; ++mf) {
        int r = wm * 64 + mf * 16 + (lane & 15);
        int slot = (ks * 4 + (lane >> 4)) ^ (r & 7);
        af[mf] = *(const bf16x8*)&Asm[r * 64 + slot * 8];
      }
#pragma unroll
      for (int nf = 0; nf < 4; ++nf) {
        int r = wn * 64 + nf * 16 + (lane & 15);
        int slot = (ks * 4 + (lane >> 4)) ^ (r & 7);
        bfr[nf] = *(const bf16x8*)&Bsm[r * 64 + slot * 8];
      }
#pragma unroll
      for (int mf = 0; mf < 4; ++mf)
#pragma unroll
        for (int nf = 0; nf < 4; ++nf)
          acc[mf][nf] = __builtin_amdgcn_mfma_f32_16x16x32_bf16(af[mf], bfr[nf], acc[mf][nf], 0, 0, 0);
    }
    __syncthreads();
  }
#pragma unroll
  for (int mf = 0; mf < 4; ++mf)
#pragma unroll
    for (int nf = 0; nf < 4; ++nf) {
      int col = j0 + wn * 64 + nf * 16 + (lane & 15);
#pragma unroll
      for (int r = 0; r < 4; ++r) {
        int rrow = m0 + wm * 64 + mf * 16 + (lane >> 4) * 4 + r;
        tmp[(size_t)rrow * 51200 + col] = f2bf(acc[mf][nf][r]);
      }
    }
}

// ---------------------------------------------------------------- k_S
__global__ __launch_bounds__(512) void k_S(const unsigned short* __restrict__ tmp,
                                           const float* __restrict__ vw,
                                           float* __restrict__ S) {
  __shared__ float vs[512];
  __shared__ float part[512];
  const int m = blockIdx.x;
  const int tid = threadIdx.x;
  if (tid < 512) vs[tid] = vw[m * 512 + tid];
  __syncthreads();
  const int quad = tid >> 7, n = tid & 127;
  float acc = 0.f;
  if (n < 100) {
    const unsigned short* tr = tmp + (size_t)m * 51200 + n;
#pragma unroll 8
    for (int ky = quad * 128; ky < quad * 128 + 128; ++ky) acc += bf2f(tr[(size_t)ky * 100]) * vs[ky];
  }
  part[tid] = acc;
  __syncthreads();
  if (tid < 100)
    S[m * 100 + tid] = part[tid] + part[128 + tid] + part[256 + tid] + part[384 + tid];
}

// ---------------------------------------------------------------- k_scan
__global__ __launch_bounds__(1024) void k_scan(const float* __restrict__ Ann,
                                               const float* __restrict__ Sg,
                                               float* __restrict__ ug) {
  __shared__ float Abuf[10000];
  __shared__ float s_s[800];
  __shared__ float u_s[800];
  __shared__ float red[16];
  __shared__ int stopflag;
  const int tid = threadIdx.x;

  for (int f = tid; f < 10000; f += 1024) Abuf[f] = Ann[f];
  for (int f = tid; f < 800; f += 1024) {
    int bp = f / 100, n = f - bp * 100;
    u_s[f] = Sg[(bp * 32 + 30) * 100 + n];
  }
  const int ri = tid / 25;
  const int cj = tid - ri * 25;
  const bool sqact = (tid < 625);
  __syncthreads();

  for (int i = 0; i < 30; ++i) {
    const int t = 29 - i;
    for (int f = tid; f < 800; f += 1024) {
      int bp = f / 100, n = f - bp * 100;
      s_s[f] = Sg[(bp * 32 + t) * 100 + n];
    }
    __syncthreads();
    if (tid < 800) {
      int bp = tid / 100, n = tid - bp * 100;
      const float* Ar = &Abuf[n * 100];
      const float* sr = &s_s[bp * 100];
      float a0 = 0.f;
#pragma unroll
      for (int mm = 0; mm < 100; mm += 4) {
        float4 a4 = ld4(Ar + mm);
        float4 s4 = ld4(sr + mm);
        a0 += a4.x * s4.x + a4.y * s4.y + a4.z * s4.z + a4.w * s4.w;
      }
      u_s[tid] += a0;
    }
    if (i == 29) break;

    float acc2[4][4];
    float lmax = 0.f;
    if (sqact) {
#pragma unroll
      for (int a = 0; a < 4; ++a)
#pragma unroll
        for (int b = 0; b < 4; ++b) acc2[a][b] = 0.f;
      for (int mm = 0; mm < 100; mm += 4) {
        float av[4][4], bv[4][4];
#pragma unroll
        for (int ii = 0; ii < 4; ++ii)
          *(float4*)&av[ii][0] = ld4(&Abuf[(ri * 4 + ii) * 100 + mm]);
#pragma unroll
        for (int mi = 0; mi < 4; ++mi)
          *(float4*)&bv[mi][0] = ld4(&Abuf[(mm + mi) * 100 + cj * 4]);
#pragma unroll
        for (int ii = 0; ii < 4; ++ii)
#pragma unroll
          for (int mi = 0; mi < 4; ++mi)
#pragma unroll
            for (int qq = 0; qq < 4; ++qq) acc2[ii][qq] += av[ii][mi] * bv[mi][qq];
      }
    }
    __syncthreads();
    if (sqact) {
#pragma unroll
      for (int ii = 0; ii < 4; ++ii) {
        float4 wv = make_float4(acc2[ii][0], acc2[ii][1], acc2[ii][2], acc2[ii][3]);
        *(float4*)&Abuf[(ri * 4 + ii) * 100 + cj * 4] = wv;
        lmax = fmaxf(lmax, fmaxf(fmaxf(fabsf(wv.x), fabsf(wv.y)), fmaxf(fabsf(wv.z), fabsf(wv.w))));
      }
    }
#pragma unroll
    for (int off = 32; off > 0; off >>= 1) lmax = fmaxf(lmax, __shfl_down(lmax, off, 64));
    if ((tid & 63) == 0) red[tid >> 6] = lmax;
    __syncthreads();
    if (tid == 0) {
      float mx = 0.f;
      for (int wv = 0; wv < 16; ++wv) mx = fmaxf(mx, red[wv]);
      stopflag = (mx < 1e-28f) ? 1 : 0;
    }
    __syncthreads();
    if (stopflag) break;
  }
  __syncthreads();
  for (int f = tid; f < 800; f += 1024) ug[f] = u_s[f];
}

// ---------------------------------------------------------------- k_h
__global__ __launch_bounds__(256) void k_h(const float* __restrict__ Aon,
                                           const float* __restrict__ Aoo,
                                           const float* __restrict__ kw,
                                           const float* __restrict__ vw,
                                           const float* __restrict__ ug,
                                           float* __restrict__ h) {
  __shared__ float uT[100 * 8];
  __shared__ float aoo_s[64];
  __shared__ float kl_s[8];
  __shared__ float vl_s[8 * 64];
  __shared__ float part[4 * 64 * 8];
  const int bid = blockIdx.x;  // (a*8+b)*64+g
  const int g = bid & 63, b = (bid >> 6) & 7, a = bid >> 9;
  const int tid = threadIdx.x;

  for (int f = tid; f < 800; f += 256) {
    int n = f >> 3, bp = f & 7;
    uT[f] = ug[bp * 100 + n];
  }
  if (tid < 64) aoo_s[tid] = Aoo[(size_t)bid * 64 + tid];
  if (tid < 8) kl_s[tid] = kw[(size_t)(tid * 32 + 31) * 512 + a * 64 + g];
  for (int f = tid; f < 512; f += 256) {
    int bp = f >> 6, d = f & 63;
    vl_s[f] = vw[(size_t)(bp * 32 + 31) * 512 + b * 64 + d];
  }
  __syncthreads();

  const int ng = tid & 3, d = tid >> 2;
  float ar[25];
  {
    const float* basep = Aon + (size_t)(bid * 64 + d) * 100 + ng * 25;
#pragma unroll
    for (int q = 0; q < 25; ++q) ar[q] = basep[q];
  }
  float acc8[8];
#pragma unroll
  for (int bb = 0; bb < 8; ++bb) acc8[bb] = 0.f;
#pragma unroll
  for (int q = 0; q < 25; ++q) {
    int n = ng * 25 + q;
    float av = ar[q];
    float4 u0 = ld4(&uT[n * 8]);
    float4 u1 = ld4(&uT[n * 8 + 4]);
    acc8[0] += av * u0.x; acc8[1] += av * u0.y; acc8[2] += av * u0.z; acc8[3] += av * u0.w;
    acc8[4] += av * u1.x; acc8[5] += av * u1.y; acc8[6] += av * u1.z; acc8[7] += av * u1.w;
  }
  {
    float* pp = &part[(ng * 64 + d) * 8];
    *(float4*)pp = make_float4(acc8[0], acc8[1], acc8[2], acc8[3]);
    *(float4*)(pp + 4) = make_float4(acc8[4], acc8[5], acc8[6], acc8[7]);
  }
  __syncthreads();
  for (int o = tid; o < 512; o += 256) {
    int bp = o >> 6, d2 = o & 63;
    float s = aoo_s[d2] * kl_s[bp] * vl_s[bp * 64 + d2];
#pragma unroll
    for (int n2 = 0; n2 < 4; ++n2) s += part[(n2 * 64 + d2) * 8 + bp];
    h[(size_t)bp * 262144 + (size_t)bid * 64 + d2] = s;
  }
}

// ---------------------------------------------------------------- k_y
__global__ __launch_bounds__(256) void k_y(const float* __restrict__ qw,
                                           const float* __restrict__ h,
                                           float* __restrict__ out) {
  __shared__ float qT[32 * 32];
  __shared__ float Hs[32 * 64];
  const int bid = blockIdx.x;  // bp*8 + b
  const int bp = bid >> 3, b = bid & 7;
  const int tid = threadIdx.x;
  const int r2 = tid >> 4, c2 = tid & 15;
  const size_t hbase = (size_t)bp * 262144 + (size_t)b * 4096;
  float acc[2][4];
#pragma unroll
  for (int i = 0; i < 2; ++i)
#pragma unroll
    for (int q = 0; q < 4; ++q) acc[i][q] = 0.f;

  for (int kc = 0; kc < 512; kc += 32) {
    {
      int t = tid & 31, kq = tid >> 5;
      float4 qv = ld4(qw + (size_t)(bp * 32 + t) * 512 + kc + kq * 4);
      qT[(kq * 4 + 0) * 32 + t] = qv.x;
      qT[(kq * 4 + 1) * 32 + t] = qv.y;
      qT[(kq * 4 + 2) * 32 + t] = qv.z;
      qT[(kq * 4 + 3) * 32 + t] = qv.w;
    }
#pragma unroll
    for (int i2 = 0; i2 < 2; ++i2) {
      int fid = i2 * 256 + tid;
      int kk = fid >> 4, xq = (fid & 15) * 4;
      int row = kc + kk;
      int A = row >> 6, G = row & 63;
      float4 hv = ld4(h + hbase + (size_t)A * 32768 + (size_t)G * 64 + xq);
      *(float4*)&Hs[kk * 64 + xq] = hv;
    }
    __syncthreads();
#pragma unroll
    for (int kk = 0; kk < 32; ++kk) {
      float2 q2 = *(const float2*)&qT[kk * 32 + r2 * 2];
      float4 h4 = ld4(&Hs[kk * 64 + c2 * 4]);
      acc[0][0] += q2.x * h4.x; acc[0][1] += q2.x * h4.y; acc[0][2] += q2.x * h4.z; acc[0][3] += q2.x * h4.w;
      acc[1][0] += q2.y * h4.x; acc[1][1] += q2.y * h4.y; acc[1][2] += q2.y * h4.z; acc[1][3] += q2.y * h4.w;
    }
    __syncthreads();
  }
#pragma unroll
  for (int i = 0; i < 2; ++i) {
    float4 v = make_float4(acc[i][0], acc[i][1], acc[i][2], acc[i][3]);
    *(float4*)&out[(size_t)(bp * 32 + r2 * 2 + i) * 512 + b * 64 + c2 * 4] = v;
  }
}

// ---------------------------------------------------------------- launch
extern "C" void kernel_launch(void* const* d_in, const int* in_sizes, int n_in,
                              void* d_out, int out_size, void* d_ws, size_t ws_size,
                              hipStream_t stream) {
  const float* x   = (const float*)d_in[0];
  const float* K   = (const float*)d_in[1];
  const float* Q   = (const float*)d_in[2];
  const float* V   = (const float*)d_in[3];
  const float* Aoo = (const float*)d_in[4];
  const float* Ann = (const float*)d_in[5];
  const float* Aon = (const float*)d_in[6];
  const float* Ano = (const float*)d_in[7];
  float* out = (float*)d_out;

  float* ws = (float*)d_ws;
  // float-offset layout (~42 MB):
  float* kw  = ws;                                          // 131072
  float* qw  = kw + 131072;                                 // 131072
  float* vw  = qw + 131072;                                 // 131072
  unsigned short* kwb = (unsigned short*)(vw + 131072);     // 131072 u16 = 65536 f
  float* S   = ws + 458752;                                 // 25600
  float* u   = S + 25600;                                   // 800
  unsigned short* A2  = (unsigned short*)(ws + 485152);     // 393216 u16 = 196608 f
  unsigned short* Bw  = (unsigned short*)(ws + 681760);     // 2359296 u16 = 1179648 f
  float* h   = ws + 1861408;                                // 2097152 f
  unsigned short* tmp = (unsigned short*)(ws + 3958560);    // 13107200 u16 = 6553600 f

  k_prep<<<dim3(256), dim3(256), 0, stream>>>(x, A2);
  k_cvtW<<<dim3(1536), dim3(128), 0, stream>>>(K, Q, V, Bw);
  k_kqv3<<<dim3(24), dim3(256), 0, stream>>>(A2, Bw, kw, kwb);
  k_gemm2<<<dim3(800), dim3(256), 0, stream>>>(kwb, Ano, tmp);
  k_S<<<dim3(256), dim3(512), 0, stream>>>(tmp, vw, S);
  k_scan<<<dim3(1), dim3(1024), 0, stream>>>(Ann, S, u);
  k_h<<<dim3(4096), dim3(256), 0, stream>>>(Aon, Aoo, kw, vw, u, h);
  k_y<<<dim3(64), dim3(256), 0, stream>>>(qw, h, out);
}

// Round 5
// 183.904 us; speedup vs baseline: 2.4966x; 1.1458x over previous
//
#include <hip/hip_runtime.h>

// GateLoopOperator, MI355X. Round 5:
//  - k_gemm2 B staging made coalesced (row-segment loads) + new B-side XOR swizzle
//  - k_scan: early-exit threshold raised (1e-28 -> 1e-6 on max|A|, checked BEFORE squaring)
//
// Pipeline:
//  k_prep : A2[m][1536] bf16 = [hi(xp) | hi(xp) | lo(xp)], xp[m][x*8+c]=x[m][c*64+x]
//  k_cvtW : Bw[j=mat*512+o][1536] bf16 = [hi(W_mat[r(o)]) | lo | hi], r(o)=((o&63)<<3)|(o>>6)
//  k_kqv3 : kqvF[mat][m][o] f32 = A2 @ Bw^T  (MFMA, split-bf16 => f32 quality) + kwb bf16
//  k_gemm2: tmp[m][j] bf16 = kwb[m][:] . Ano[:, j]  (M=256,J=51200,K=512; B from f32 Ano)
//  k_S    : S[m,n] = sum_{ky} tmp[m][ky*100+n] * v[m][ky]
//  k_scan : u[bp,n] = S[bp,30] + sum_i Ann^(2^i) @ S[bp,29-i]  (serial, early-exit)
//  k_h    : h[bp,a,b,g,d] = Aoo*k_last*v_last + Aon . u
//  k_y    : y[bpt,b,d] = sum_{a,g} q[bpt,ag] * h[bp,a,b,g,d]

#define ANO_C_STR 3276800
#define ANO_K_STR 409600
#define ANO_X_STR 6400

typedef __attribute__((ext_vector_type(8))) short bf16x8;
typedef __attribute__((ext_vector_type(4))) float f32x4;
typedef __attribute__((ext_vector_type(4))) unsigned short u16x4;

__device__ __forceinline__ float4 ld4(const float* p) { return *(const float4*)p; }

__device__ __forceinline__ unsigned short f2bf(float f) {  // RNE
  unsigned u = __float_as_uint(f);
  unsigned r = (u + 0x7fffu + ((u >> 16) & 1u)) >> 16;
  return (unsigned short)r;
}
__device__ __forceinline__ float bf2f(unsigned short b) {
  return __uint_as_float(((unsigned)b) << 16);
}

// ---------------------------------------------------------------- k_prep
__global__ __launch_bounds__(256) void k_prep(const float* __restrict__ X,
                                              unsigned short* __restrict__ A2) {
  __shared__ float xs[512];
  const int m = blockIdx.x;
  const int tid = threadIdx.x;
  for (int f = tid; f < 512; f += 256) xs[f] = X[m * 512 + f];
  __syncthreads();
  for (int f = tid; f < 512; f += 256) {
    float v = xs[((f & 7) << 6) | (f >> 3)];
    unsigned short hi = f2bf(v);
    unsigned short lo = f2bf(v - bf2f(hi));
    A2[(size_t)m * 1536 + f] = hi;
    A2[(size_t)m * 1536 + 512 + f] = hi;
    A2[(size_t)m * 1536 + 1024 + f] = lo;
  }
}

// ---------------------------------------------------------------- k_cvtW
__global__ __launch_bounds__(128) void k_cvtW(const float* __restrict__ Km,
                                              const float* __restrict__ Qm,
                                              const float* __restrict__ Vm,
                                              unsigned short* __restrict__ Bw) {
  const int j = blockIdx.x;  // mat*512 + o
  const int mat = j >> 9, o = j & 511;
  const int r = ((o & 63) << 3) | (o >> 6);
  const float* W = ((mat == 0) ? Km : ((mat == 1) ? Qm : Vm)) + (size_t)r * 512;
  const int tid = threadIdx.x;
  float4 v = ld4(W + tid * 4);
  u16x4 hi, lo;
  float vv[4] = {v.x, v.y, v.z, v.w};
#pragma unroll
  for (int e = 0; e < 4; ++e) {
    hi[e] = f2bf(vv[e]);
    lo[e] = f2bf(vv[e] - bf2f(hi[e]));
  }
  *(u16x4*)&Bw[(size_t)j * 1536 + tid * 4] = hi;
  *(u16x4*)&Bw[(size_t)j * 1536 + 512 + tid * 4] = lo;
  *(u16x4*)&Bw[(size_t)j * 1536 + 1024 + tid * 4] = hi;
}

// ---------------------------------------------------------------- k_kqv3
__global__ __launch_bounds__(256) void k_kqv3(const unsigned short* __restrict__ A2,
                                              const unsigned short* __restrict__ Bw,
                                              float* __restrict__ kqvF,
                                              unsigned short* __restrict__ kwb) {
  __shared__ __align__(16) unsigned short Asm[128 * 64];
  __shared__ __align__(16) unsigned short Bsm[128 * 64];
  const int bid = blockIdx.x;  // 24
  const int mt = bid & 1, jt = bid >> 1;
  const int m0 = mt * 128, j0 = jt * 128;
  const int tid = threadIdx.x;
  const int lane = tid & 63;
  const int w = tid >> 6;
  const int wm = w >> 1, wn = w & 1;

  f32x4 acc[4][4];
#pragma unroll
  for (int a = 0; a < 4; ++a)
#pragma unroll
    for (int b = 0; b < 4; ++b) acc[a][b] = (f32x4)(0.f);

  for (int kc = 0; kc < 1536; kc += 64) {
#pragma unroll
    for (int cch = 0; cch < 4; ++cch) {
      int sid = cch * 256 + tid;
      int r = sid >> 3, c8 = sid & 7;
      int srcc = c8 ^ (r & 7);
      const unsigned short* ga = A2 + (size_t)(m0 + r) * 1536 + kc + srcc * 8;
      __builtin_amdgcn_global_load_lds((const __attribute__((address_space(1))) unsigned int*)ga,
                                       (__attribute__((address_space(3))) unsigned int*)(&Asm[sid * 8]),
                                       16, 0, 0);
      const unsigned short* gb = Bw + (size_t)(j0 + r) * 1536 + kc + srcc * 8;
      __builtin_amdgcn_global_load_lds((const __attribute__((address_space(1))) unsigned int*)gb,
                                       (__attribute__((address_space(3))) unsigned int*)(&Bsm[sid * 8]),
                                       16, 0, 0);
    }
    __syncthreads();
#pragma unroll
    for (int ks = 0; ks < 2; ++ks) {
      bf16x8 af[4], bfr[4];
#pragma unroll
      for (int mf = 0; mf < 4; ++mf) {
        int r = wm * 64 + mf * 16 + (lane & 15);
        int slot = (ks * 4 + (lane >> 4)) ^ (r & 7);
        af[mf] = *(const bf16x8*)&Asm[r * 64 + slot * 8];
      }
#pragma unroll
      for (int nf = 0; nf < 4; ++nf) {
        int r = wn * 64 + nf * 16 + (lane & 15);
        int slot = (ks * 4 + (lane >> 4)) ^ (r & 7);
        bfr[nf] = *(const bf16x8*)&Bsm[r * 64 + slot * 8];
      }
#pragma unroll
      for (int mf = 0; mf < 4; ++mf)
#pragma unroll
        for (int nf = 0; nf < 4; ++nf)
          acc[mf][nf] = __builtin_amdgcn_mfma_f32_16x16x32_bf16(af[mf], bfr[nf], acc[mf][nf], 0, 0, 0);
    }
    __syncthreads();
  }
#pragma unroll
  for (int mf = 0; mf < 4; ++mf)
#pragma unroll
    for (int nf = 0; nf < 4; ++nf) {
      int col = j0 + wn * 64 + nf * 16 + (lane & 15);
      int mat = col >> 9, o = col & 511;
      float* Outp = kqvF + (size_t)mat * 131072;
#pragma unroll
      for (int r = 0; r < 4; ++r) {
        int row = m0 + wm * 64 + mf * 16 + (lane >> 4) * 4 + r;
        float val = acc[mf][nf][r];
        Outp[(size_t)row * 512 + o] = val;
        if (mat == 0) kwb[(size_t)row * 512 + o] = f2bf(val);
      }
    }
}

// ---------------------------------------------------------------- k_gemm2
// tmp[256][51200] bf16 = kwb @ AnoMat. B staged from f32 Ano with COALESCED loads:
// per instruction lanes 0-31 / 32-63 read two contiguous 512B row segments.
// Thread owns rows {2ta, 2ta+1} (ta = it*8 + w*2 + (lane>>5)), cols 4*bcol..+3.
// B LDS swizzle: u32 word (j, a=ta) at j*32 + (a ^ (((j>>2)&7)<<2));
// frag read slot = (ks*4 + lane>>4) ^ ((j>>2)&7)  (16B-aligned, a-consecutive).
__global__ __launch_bounds__(256) void k_gemm2(const unsigned short* __restrict__ Abf,
                                               const float* __restrict__ Ano,
                                               unsigned short* __restrict__ tmp) {
  __shared__ __align__(16) unsigned short Asm[128 * 64];
  __shared__ __align__(16) unsigned short Bsm[128 * 64];
  const int bid = blockIdx.x;  // 800; bid and bid+8 share jt -> same XCD L2 reuse of Ano
  const int jt = ((bid >> 4) << 3) | (bid & 7);
  const int mt = (bid >> 3) & 1;
  const int m0 = mt * 128;
  const int j0 = jt * 128;
  const int tid = threadIdx.x;
  const int lane = tid & 63;
  const int w = tid >> 6;
  const int wm = w >> 1, wn = w & 1;
  const int k2 = j0 / 6400;
  const int jloc = j0 - k2 * 6400;
  const float* anoBase = Ano + (size_t)k2 * ANO_K_STR + jloc;
  const int bcol = lane & 31;             // float4 col index within the 128-col tile
  const int rbase = w * 2 + (lane >> 5);  // 0..7

  f32x4 acc[4][4];
#pragma unroll
  for (int a = 0; a < 4; ++a)
#pragma unroll
    for (int b = 0; b < 4; ++b) acc[a][b] = (f32x4)(0.f);

  for (int kc = 0; kc < 512; kc += 64) {
    const float* anoC = anoBase + (size_t)(kc >> 6) * ANO_C_STR;
    // coalesced B-tile loads: 8 x (two 512B contiguous segments per instruction)
    float4 bx0[4], bx1[4];
#pragma unroll
    for (int it = 0; it < 4; ++it) {
      int ta = it * 8 + rbase;
      const float* p0 = anoC + (size_t)(2 * ta) * ANO_X_STR + bcol * 4;
      bx0[it] = ld4(p0);
      bx1[it] = ld4(p0 + ANO_X_STR);
    }
    // A tile via global_load_lds (source-swizzled, unchanged)
#pragma unroll
    for (int cch = 0; cch < 4; ++cch) {
      int sid = cch * 256 + tid;
      int r = sid >> 3, c8 = sid & 7;
      int srcc = c8 ^ (r & 7);
      const unsigned short* ga = Abf + (size_t)(m0 + r) * 512 + kc + srcc * 8;
      __builtin_amdgcn_global_load_lds((const __attribute__((address_space(1))) unsigned int*)ga,
                                       (__attribute__((address_space(3))) unsigned int*)(&Asm[sid * 8]),
                                       16, 0, 0);
    }
    // cvt + pack k-pairs + swizzled ds_write of B
    unsigned* bdst = (unsigned*)Bsm;
#pragma unroll
    for (int it = 0; it < 4; ++it) {
      int ta = it * 8 + rbase;
      float v0[4] = {bx0[it].x, bx0[it].y, bx0[it].z, bx0[it].w};
      float v1[4] = {bx1[it].x, bx1[it].y, bx1[it].z, bx1[it].w};
#pragma unroll
      for (int e = 0; e < 4; ++e) {
        int j = 4 * bcol + e;
        unsigned pk = (unsigned)f2bf(v0[e]) | ((unsigned)f2bf(v1[e]) << 16);
        bdst[j * 32 + (ta ^ (((j >> 2) & 7) << 2))] = pk;
      }
    }
    __syncthreads();
#pragma unroll
    for (int ks = 0; ks < 2; ++ks) {
      bf16x8 af[4], bfr[4];
#pragma unroll
      for (int mf = 0; mf < 4; ++mf) {
        int r = wm * 64 + mf * 16 + (lane & 15);
        int slot = (ks * 4 + (lane >> 4)) ^ (r & 7);
        af[mf] = *(const bf16x8*)&Asm[r * 64 + slot * 8];
      }
#pragma unroll
      for (int nf = 0; nf < 4; ++nf) {
        int r = wn * 64 + nf * 16 + (lane & 15);
        int slot = (ks * 4 + (lane >> 4)) ^ ((r >> 2) & 7);
        bfr[nf] = *(const bf16x8*)&Bsm[r * 64 + slot * 8];
      }
#pragma unroll
      for (int mf = 0; mf < 4; ++mf)
#pragma unroll
        for (int nf = 0; nf < 4; ++nf)
          acc[mf][nf] = __builtin_amdgcn_mfma_f32_16x16x32_bf16(af[mf], bfr[nf], acc[mf][nf], 0, 0, 0);
    }
    __syncthreads();
  }
#pragma unroll
  for (int mf = 0; mf < 4; ++mf)
#pragma unroll
    for (int nf = 0; nf < 4; ++nf) {
      int col = j0 + wn * 64 + nf * 16 + (lane & 15);
#pragma unroll
      for (int r = 0; r < 4; ++r) {
        int rrow = m0 + wm * 64 + mf * 16 + (lane >> 4) * 4 + r;
        tmp[(size_t)rrow * 51200 + col] = f2bf(acc[mf][nf][r]);
      }
    }
}

// ---------------------------------------------------------------- k_S
__global__ __launch_bounds__(512) void k_S(const unsigned short* __restrict__ tmp,
                                           const float* __restrict__ vw,
                                           float* __restrict__ S) {
  __shared__ float vs[512];
  __shared__ float part[512];
  const int m = blockIdx.x;
  const int tid = threadIdx.x;
  if (tid < 512) vs[tid] = vw[m * 512 + tid];
  __syncthreads();
  const int quad = tid >> 7, n = tid & 127;
  float acc = 0.f;
  if (n < 100) {
    const unsigned short* tr = tmp + (size_t)m * 51200 + n;
#pragma unroll 8
    for (int ky = quad * 128; ky < quad * 128 + 128; ++ky) acc += bf2f(tr[(size_t)ky * 100]) * vs[ky];
  }
  part[tid] = acc;
  __syncthreads();
  if (tid < 100)
    S[m * 100 + tid] = part[tid] + part[128 + tid] + part[256 + tid] + part[384 + tid];
}

// ---------------------------------------------------------------- k_scan
// u[bp] = S[bp,30] + sum_i A^(2^i) @ S[bp,29-i]; stop once max|A| < 1e-6
// (skipped terms bounded by 100*max|A|^2*100*|s| ~ 1e-6, vs output threshold 15.76).
__global__ __launch_bounds__(1024) void k_scan(const float* __restrict__ Ann,
                                               const float* __restrict__ Sg,
                                               float* __restrict__ ug) {
  __shared__ float Abuf[10000];
  __shared__ float s_s[800];
  __shared__ float u_s[800];
  __shared__ float red[16];
  __shared__ float gmax_s;
  const int tid = threadIdx.x;

  float lmax0 = 0.f;
  for (int f = tid; f < 10000; f += 1024) {
    float a = Ann[f];
    Abuf[f] = a;
    lmax0 = fmaxf(lmax0, fabsf(a));
  }
  for (int f = tid; f < 800; f += 1024) {
    int bp = f / 100, n = f - bp * 100;
    u_s[f] = Sg[(bp * 32 + 30) * 100 + n];
  }
#pragma unroll
  for (int off = 32; off > 0; off >>= 1) lmax0 = fmaxf(lmax0, __shfl_down(lmax0, off, 64));
  if ((tid & 63) == 0) red[tid >> 6] = lmax0;
  __syncthreads();
  if (tid == 0) {
    float mx = 0.f;
    for (int wv = 0; wv < 16; ++wv) mx = fmaxf(mx, red[wv]);
    gmax_s = mx;
  }
  const int ri = tid / 25;
  const int cj = tid - ri * 25;
  const bool sqact = (tid < 625);
  __syncthreads();

  for (int i = 0; i < 30; ++i) {
    const int t = 29 - i;
    for (int f = tid; f < 800; f += 1024) {
      int bp = f / 100, n = f - bp * 100;
      s_s[f] = Sg[(bp * 32 + t) * 100 + n];
    }
    __syncthreads();
    if (tid < 800) {
      int bp = tid / 100, n = tid - bp * 100;
      const float* Ar = &Abuf[n * 100];
      const float* sr = &s_s[bp * 100];
      float a0 = 0.f;
#pragma unroll
      for (int mm = 0; mm < 100; mm += 4) {
        float4 a4 = ld4(Ar + mm);
        float4 s4 = ld4(sr + mm);
        a0 += a4.x * s4.x + a4.y * s4.y + a4.z * s4.z + a4.w * s4.w;
      }
      u_s[tid] += a0;
    }
    if (i == 29) break;
    if (gmax_s < 1e-6f) break;  // remaining terms negligible; skip the squaring too

    float acc2[4][4];
    float lmax = 0.f;
    if (sqact) {
#pragma unroll
      for (int a = 0; a < 4; ++a)
#pragma unroll
        for (int b = 0; b < 4; ++b) acc2[a][b] = 0.f;
      for (int mm = 0; mm < 100; mm += 4) {
        float av[4][4], bv[4][4];
#pragma unroll
        for (int ii = 0; ii < 4; ++ii)
          *(float4*)&av[ii][0] = ld4(&Abuf[(ri * 4 + ii) * 100 + mm]);
#pragma unroll
        for (int mi = 0; mi < 4; ++mi)
          *(float4*)&bv[mi][0] = ld4(&Abuf[(mm + mi) * 100 + cj * 4]);
#pragma unroll
        for (int ii = 0; ii < 4; ++ii)
#pragma unroll
          for (int mi = 0; mi < 4; ++mi)
#pragma unroll
            for (int qq = 0; qq < 4; ++qq) acc2[ii][qq] += av[ii][mi] * bv[mi][qq];
      }
    }
    __syncthreads();
    if (sqact) {
#pragma unroll
      for (int ii = 0; ii < 4; ++ii) {
        float4 wv = make_float4(acc2[ii][0], acc2[ii][1], acc2[ii][2], acc2[ii][3]);
        *(float4*)&Abuf[(ri * 4 + ii) * 100 + cj * 4] = wv;
        lmax = fmaxf(lmax, fmaxf(fmaxf(fabsf(wv.x), fabsf(wv.y)), fmaxf(fabsf(wv.z), fabsf(wv.w))));
      }
    }
#pragma unroll
    for (int off = 32; off > 0; off >>= 1) lmax = fmaxf(lmax, __shfl_down(lmax, off, 64));
    if ((tid & 63) == 0) red[tid >> 6] = lmax;
    __syncthreads();
    if (tid == 0) {
      float mx = 0.f;
      for (int wv = 0; wv < 16; ++wv) mx = fmaxf(mx, red[wv]);
      gmax_s = mx;
    }
    __syncthreads();
  }
  __syncthreads();
  for (int f = tid; f < 800; f += 1024) ug[f] = u_s[f];
}

// ---------------------------------------------------------------- k_h
__global__ __launch_bounds__(256) void k_h(const float* __restrict__ Aon,
                                           const float* __restrict__ Aoo,
                                           const float* __restrict__ kw,
                                           const float* __restrict__ vw,
                                           const float* __restrict__ ug,
                                           float* __restrict__ h) {
  __shared__ float uT[100 * 8];
  __shared__ float aoo_s[64];
  __shared__ float kl_s[8];
  __shared__ float vl_s[8 * 64];
  __shared__ float part[4 * 64 * 8];
  const int bid = blockIdx.x;  // (a*8+b)*64+g
  const int g = bid & 63, b = (bid >> 6) & 7, a = bid >> 9;
  const int tid = threadIdx.x;

  for (int f = tid; f < 800; f += 256) {
    int n = f >> 3, bp = f & 7;
    uT[f] = ug[bp * 100 + n];
  }
  if (tid < 64) aoo_s[tid] = Aoo[(size_t)bid * 64 + tid];
  if (tid < 8) kl_s[tid] = kw[(size_t)(tid * 32 + 31) * 512 + a * 64 + g];
  for (int f = tid; f < 512; f += 256) {
    int bp = f >> 6, d = f & 63;
    vl_s[f] = vw[(size_t)(bp * 32 + 31) * 512 + b * 64 + d];
  }
  __syncthreads();

  const int ng = tid & 3, d = tid >> 2;
  float ar[25];
  {
    const float* basep = Aon + (size_t)(bid * 64 + d) * 100 + ng * 25;
#pragma unroll
    for (int q = 0; q < 25; ++q) ar[q] = basep[q];
  }
  float acc8[8];
#pragma unroll
  for (int bb = 0; bb < 8; ++bb) acc8[bb] = 0.f;
#pragma unroll
  for (int q = 0; q < 25; ++q) {
    int n = ng * 25 + q;
    float av = ar[q];
    float4 u0 = ld4(&uT[n * 8]);
    float4 u1 = ld4(&uT[n * 8 + 4]);
    acc8[0] += av * u0.x; acc8[1] += av * u0.y; acc8[2] += av * u0.z; acc8[3] += av * u0.w;
    acc8[4] += av * u1.x; acc8[5] += av * u1.y; acc8[6] += av * u1.z; acc8[7] += av * u1.w;
  }
  {
    float* pp = &part[(ng * 64 + d) * 8];
    *(float4*)pp = make_float4(acc8[0], acc8[1], acc8[2], acc8[3]);
    *(float4*)(pp + 4) = make_float4(acc8[4], acc8[5], acc8[6], acc8[7]);
  }
  __syncthreads();
  for (int o = tid; o < 512; o += 256) {
    int bp = o >> 6, d2 = o & 63;
    float s = aoo_s[d2] * kl_s[bp] * vl_s[bp * 64 + d2];
#pragma unroll
    for (int n2 = 0; n2 < 4; ++n2) s += part[(n2 * 64 + d2) * 8 + bp];
    h[(size_t)bp * 262144 + (size_t)bid * 64 + d2] = s;
  }
}

// ---------------------------------------------------------------- k_y
__global__ __launch_bounds__(256) void k_y(const float* __restrict__ qw,
                                           const float* __restrict__ h,
                                           float* __restrict__ out) {
  __shared__ float qT[32 * 32];
  __shared__ float Hs[32 * 64];
  const int bid = blockIdx.x;  // bp*8 + b
  const int bp = bid >> 3, b = bid & 7;
  const int tid = threadIdx.x;
  const int r2 = tid >> 4, c2 = tid & 15;
  const size_t hbase = (size_t)bp * 262144 + (size_t)b * 4096;
  float acc[2][4];
#pragma unroll
  for (int i = 0; i < 2; ++i)
#pragma unroll
    for (int q = 0; q < 4; ++q) acc[i][q] = 0.f;

  for (int kc = 0; kc < 512; kc += 32) {
    {
      int t = tid & 31, kq = tid >> 5;
      float4 qv = ld4(qw + (size_t)(bp * 32 + t) * 512 + kc + kq * 4);
      qT[(kq * 4 + 0) * 32 + t] = qv.x;
      qT[(kq * 4 + 1) * 32 + t] = qv.y;
      qT[(kq * 4 + 2) * 32 + t] = qv.z;
      qT[(kq * 4 + 3) * 32 + t] = qv.w;
    }
#pragma unroll
    for (int i2 = 0; i2 < 2; ++i2) {
      int fid = i2 * 256 + tid;
      int kk = fid >> 4, xq = (fid & 15) * 4;
      int row = kc + kk;
      int A = row >> 6, G = row & 63;
      float4 hv = ld4(h + hbase + (size_t)A * 32768 + (size_t)G * 64 + xq);
      *(float4*)&Hs[kk * 64 + xq] = hv;
    }
    __syncthreads();
#pragma unroll
    for (int kk = 0; kk < 32; ++kk) {
      float2 q2 = *(const float2*)&qT[kk * 32 + r2 * 2];
      float4 h4 = ld4(&Hs[kk * 64 + c2 * 4]);
      acc[0][0] += q2.x * h4.x; acc[0][1] += q2.x * h4.y; acc[0][2] += q2.x * h4.z; acc[0][3] += q2.x * h4.w;
      acc[1][0] += q2.y * h4.x; acc[1][1] += q2.y * h4.y; acc[1][2] += q2.y * h4.z; acc[1][3] += q2.y * h4.w;
    }
    __syncthreads();
  }
#pragma unroll
  for (int i = 0; i < 2; ++i) {
    float4 v = make_float4(acc[i][0], acc[i][1], acc[i][2], acc[i][3]);
    *(float4*)&out[(size_t)(bp * 32 + r2 * 2 + i) * 512 + b * 64 + c2 * 4] = v;
  }
}

// ---------------------------------------------------------------- launch
extern "C" void kernel_launch(void* const* d_in, const int* in_sizes, int n_in,
                              void* d_out, int out_size, void* d_ws, size_t ws_size,
                              hipStream_t stream) {
  const float* x   = (const float*)d_in[0];
  const float* K   = (const float*)d_in[1];
  const float* Q   = (const float*)d_in[2];
  const float* V   = (const float*)d_in[3];
  const float* Aoo = (const float*)d_in[4];
  const float* Ann = (const float*)d_in[5];
  const float* Aon = (const float*)d_in[6];
  const float* Ano = (const float*)d_in[7];
  float* out = (float*)d_out;

  float* ws = (float*)d_ws;
  float* kw  = ws;                                          // 131072
  float* qw  = kw + 131072;                                 // 131072
  float* vw  = qw + 131072;                                 // 131072
  unsigned short* kwb = (unsigned short*)(vw + 131072);     // 131072 u16 = 65536 f
  float* S   = ws + 458752;                                 // 25600
  float* u   = S + 25600;                                   // 800
  unsigned short* A2  = (unsigned short*)(ws + 485152);     // 393216 u16 = 196608 f
  unsigned short* Bw  = (unsigned short*)(ws + 681760);     // 2359296 u16 = 1179648 f
  float* h   = ws + 1861408;                                // 2097152 f
  unsigned short* tmp = (unsigned short*)(ws + 3958560);    // 13107200 u16 = 6553600 f

  k_prep<<<dim3(256), dim3(256), 0, stream>>>(x, A2);
  k_cvtW<<<dim3(1536), dim3(128), 0, stream>>>(K, Q, V, Bw);
  k_kqv3<<<dim3(24), dim3(256), 0, stream>>>(A2, Bw, kw, kwb);
  k_gemm2<<<dim3(800), dim3(256), 0, stream>>>(kwb, Ano, tmp);
  k_S<<<dim3(256), dim3(512), 0, stream>>>(tmp, vw, S);
  k_scan<<<dim3(1), dim3(1024), 0, stream>>>(Ann, S, u);
  k_h<<<dim3(4096), dim3(256), 0, stream>>>(Aon, Aoo, kw, vw, u, h);
  k_y<<<dim3(64), dim3(256), 0, stream>>>(qw, h, out);
}